// Round 12
// baseline (335.457 us; speedup 1.0000x reference)
//
#include <hip/hip_runtime.h>
#include <hip/hip_bf16.h>

#define HIDDEN   128
#define EDGE_DIM 32
#define NNODE    50000
#define NEDGE    800000
#define KSTEPS   9
#define NFRAG    8
#define LDS_KS   8

typedef __attribute__((ext_vector_type(4))) float        f32x4;
typedef __attribute__((ext_vector_type(8))) short        bf16x8;
typedef __attribute__((ext_vector_type(4))) unsigned int u32x4;

#define BPACK_USHORTS  (KSTEPS * NFRAG * 64 * 8)   // 73728 B
#define BIAS_OFF_BYTES (BPACK_USHORTS * 2)
#define FLAG_OFF_BYTES (BIAS_OFF_BYTES + 128 * 4)
#define DATA_OFF       74752

// new-path layout: P/Q packed bf16 (12.8 MB each); no idx buffer needed
#define PP_OFF   DATA_OFF
#define QP_OFF   (PP_OFF + NNODE * HIDDEN * 2)
#define WS_NEW   (QP_OFF + NNODE * HIDDEN * 2)     // ~25.7 MB

// R8-fallback layout
#define NODE_OFF_BYTES DATA_OFF
#define IDX_OFF_BYTES  (NODE_OFF_BYTES + NNODE * HIDDEN * 2)
#define WS_R8          (IDX_OFF_BYTES + 2 * NEDGE * 4)

__device__ __forceinline__ unsigned short f2bf(float f) {
  unsigned u = __builtin_bit_cast(unsigned, f);
  u += 0x7FFFu + ((u >> 16) & 1u);
  return (unsigned short)(u >> 16);
}

__device__ __forceinline__ unsigned cvt_pk_bf16(float a, float b) {
  union { __hip_bfloat162 h; unsigned u; } cv;
  cv.h = __float22bfloat162_rn(make_float2(a, b));   // a -> low16, b -> high16
  return cv.u;
}

__device__ __forceinline__ bf16x8 pack8(f32x4 lo, f32x4 hi) {
  u32x4 u;
  u[0] = cvt_pk_bf16(lo[0], lo[1]);
  u[1] = cvt_pk_bf16(lo[2], lo[3]);
  u[2] = cvt_pk_bf16(hi[0], hi[1]);
  u[3] = cvt_pk_bf16(hi[2], hi[3]);
  return __builtin_bit_cast(bf16x8, u);
}

__device__ __forceinline__ void gload_lds16(const void* g, void* l) {
  __builtin_amdgcn_global_load_lds(
      (const __attribute__((address_space(1))) unsigned int*)g,
      (__attribute__((address_space(3))) unsigned int*)l, 16, 0, 0);
}

#define MFMA(a, b, c) __builtin_amdgcn_mfma_f32_16x16x32_bf16((a), (b), (c), 0, 0, 0)

// ---- setup 1: folded, fragment-packed B + effective bias + idx dtype flag
__global__ void setup_kernel(const float* __restrict__ W_edge,
                             const float* __restrict__ b_edge,
                             const float* __restrict__ W1,
                             const float* __restrict__ b1,
                             const void*  __restrict__ eidx,
                             unsigned short* __restrict__ Bpack,
                             float* __restrict__ bias_eff,
                             int*   __restrict__ flag64) {
  const int bid = blockIdx.x, tid = threadIdx.x;
  if (bid < 36) {
    const int pair  = bid * 2 + (tid >> 6);
    const int lane  = tid & 63;
    const int kstep = pair >> 3;
    const int f     = pair & 7;
    const int col   = f * 16 + (lane & 15);
    const int kbase = kstep * 32 + (lane >> 4) * 8;
    float vals[8];
#pragma unroll
    for (int j = 0; j < 8; ++j) {
      const int k = kbase + j;
      float val;
      if (k < 128) {
        val = W1[k * 128 + col];
      } else if (k < 256) {
        val = W1[(k + 128) * 128 + col];
      } else {
        const int kk = k - 256;
        float s = 0.f;
        for (int t = 0; t < 128; ++t)
          s = fmaf(W_edge[kk * 128 + t], W1[(128 + t) * 128 + col], s);
        val = s;
      }
      vals[j] = val;
    }
    u32x4 sv;
#pragma unroll
    for (int j = 0; j < 4; ++j)
      sv[j] = (unsigned)f2bf(vals[2 * j]) | ((unsigned)f2bf(vals[2 * j + 1]) << 16);
    *(u32x4*)(Bpack + ((kstep * NFRAG + f) * 64 + lane) * 8) = sv;
  } else {
    if (tid < 128) {
      float s = b1[tid];
      for (int t = 0; t < 128; ++t)
        s = fmaf(b_edge[t], W1[(128 + t) * 128 + tid], s);
      bias_eff[tid] = s;
    }
    if (tid == 0) {
      const unsigned* w = (const unsigned*)eidx;
      int all0 = 1;
      for (int i = 0; i < 64; ++i) all0 &= (w[2 * i + 1] == 0u) ? 1 : 0;
      *flag64 = all0;
    }
  }
}

// ---- setup 2 (R8 path only): node_features fp32 -> bf16
__global__ __launch_bounds__(256) void cvt_nodes_kernel(const float* __restrict__ nodef,
                                                        unsigned short* __restrict__ nbf) {
  const int i = blockIdx.x * 256 + threadIdx.x;
  if (i >= NNODE * HIDDEN / 8) return;
  f32x4 lo = *(const f32x4*)(nodef + i * 8);
  f32x4 hi = *(const f32x4*)(nodef + i * 8 + 4);
  *(bf16x8*)(nbf + i * 8) = pack8(lo, hi);
}

// ---- setup 3 (R8 path only): edge_index -> int32
__global__ __launch_bounds__(256) void cvt_idx_kernel(const void* __restrict__ eidx,
                                                      const int* __restrict__ flag64,
                                                      int* __restrict__ idx32) {
  const int i = blockIdx.x * 256 + threadIdx.x;
  if (i >= 2 * NEDGE) return;
  if (*flag64) idx32[i] = (int)((const long long*)eidx)[i];
  else         idx32[i] = ((const int*)eidx)[i];
}

// ---- setup 4: P = nodef@W1a + b1_eff, Q = nodef@W1c, packed bf16.
// TRANSPOSED row layout: dword d = l15*4 + k of node n holds features
// (32k+l15 | 32k+16+l15). One dwordx4 per (node, l15) covers k=0..3.
// r10 structure: 512 thr = 8 waves x 32 nodes, B staged in LDS.
__global__ __launch_bounds__(512, 2) void pq_kernel(
    const float* __restrict__ nodef,
    const unsigned short* __restrict__ Bpack,
    const float* __restrict__ bias_eff,
    unsigned* __restrict__ Pp,
    unsigned* __restrict__ Qp) {
  __shared__ unsigned short lds_b[LDS_KS * NFRAG * 64 * 8];   // 65536 B

  const int tid  = threadIdx.x;
  const int lane = tid & 63;
  const int wid  = tid >> 6;
  const int l15  = lane & 15;
  const int kg   = lane >> 4;
  const int nb   = blockIdx.x * 256 + wid * 32;

#pragma unroll
  for (int i = 0; i < 8; ++i) {
    const char* g = (const char*)Bpack + (size_t)(i * 512 + tid) * 16;
    char*       l = (char*)lds_b + (size_t)(i * 512 + wid * 64) * 16;
    gload_lds16(g, l);
  }

  const int n0 = min(nb + l15, NNODE - 1);
  const int n1 = min(nb + 16 + l15, NNODE - 1);
  bf16x8 a0[4], a1[4];
#pragma unroll
  for (int ks = 0; ks < 4; ++ks) {
    const float* p0 = nodef + (size_t)n0 * HIDDEN + ks * 32 + kg * 8;
    const float* p1 = nodef + (size_t)n1 * HIDDEN + ks * 32 + kg * 8;
    a0[ks] = pack8(*(const f32x4*)p0, *(const f32x4*)(p0 + 4));
    a1[ks] = pack8(*(const f32x4*)p1, *(const f32x4*)(p1 + 4));
  }

  float bv[NFRAG];
#pragma unroll
  for (int f = 0; f < NFRAG; ++f) bv[f] = bias_eff[f * 16 + l15];

  __syncthreads();

  // P pass (W1a = ks 0..3), bias folded
  f32x4 acc[2][NFRAG];
#pragma unroll
  for (int m = 0; m < 2; ++m)
#pragma unroll
    for (int f = 0; f < NFRAG; ++f)
      acc[m][f] = (f32x4){bv[f], bv[f], bv[f], bv[f]};
#pragma unroll
  for (int ks = 0; ks < 4; ++ks)
#pragma unroll
    for (int f = 0; f < NFRAG; ++f) {
      bf16x8 bfr = *(const bf16x8*)(lds_b + ((ks * NFRAG + f) * 64 + lane) * 8);
      acc[0][f] = MFMA(a0[ks], bfr, acc[0][f]);
      acc[1][f] = MFMA(a1[ks], bfr, acc[1][f]);
    }
#pragma unroll
  for (int m = 0; m < 2; ++m)
#pragma unroll
    for (int r = 0; r < 4; ++r) {
      const int n = nb + m * 16 + kg * 4 + r;
      if (n < NNODE) {
        u32x4 sv;
#pragma unroll
        for (int k = 0; k < 4; ++k)
          sv[k] = cvt_pk_bf16(acc[m][2 * k][r], acc[m][2 * k + 1][r]);
        *(u32x4*)(Pp + (size_t)n * 64 + l15 * 4) = sv;
      }
    }

  // Q pass (W1c = ks 4..7)
#pragma unroll
  for (int m = 0; m < 2; ++m)
#pragma unroll
    for (int f = 0; f < NFRAG; ++f)
      acc[m][f] = (f32x4){0.f, 0.f, 0.f, 0.f};
#pragma unroll
  for (int ks = 0; ks < 4; ++ks)
#pragma unroll
    for (int f = 0; f < NFRAG; ++f) {
      bf16x8 bfr = *(const bf16x8*)(lds_b + (((ks + 4) * NFRAG + f) * 64 + lane) * 8);
      acc[0][f] = MFMA(a0[ks], bfr, acc[0][f]);
      acc[1][f] = MFMA(a1[ks], bfr, acc[1][f]);
    }
#pragma unroll
  for (int m = 0; m < 2; ++m)
#pragma unroll
    for (int r = 0; r < 4; ++r) {
      const int n = nb + m * 16 + kg * 4 + r;
      if (n < NNODE) {
        u32x4 sv;
#pragma unroll
        for (int k = 0; k < 4; ++k)
          sv[k] = cvt_pk_bf16(acc[m][2 * k][r], acc[m][2 * k + 1][r]);
        *(u32x4*)(Qp + (size_t)n * 64 + l15 * 4) = sv;
      }
    }
}

// ---- main: 256 thr = 4 waves x 32 edges, grid 6250, 6 blocks/CU.
// No LDS, no barriers. Reads edge_index directly (uniform dtype branch).
__global__ __launch_bounds__(256, 6) void edge_attn_pq(
    const float* __restrict__ eattr,
    const void*  __restrict__ eidx,
    const int*   __restrict__ flag64,
    const unsigned* __restrict__ Pp,
    const unsigned* __restrict__ Qp,
    const unsigned short* __restrict__ Bpack,
    const float* __restrict__ W2,
    const float* __restrict__ b2,
    float* __restrict__ out) {
  const int tid   = threadIdx.x;
  const int lane  = tid & 63;
  const int wid   = tid >> 6;
  const int l15   = lane & 15;
  const int kg    = lane >> 4;
  const int ebase = blockIdx.x * 128 + wid * 32;

  const f32x4 zero4 = {0.f, 0.f, 0.f, 0.f};

  // indices first (critical path), C-layout rows: edge = ebase + m*16 + kg*4 + r
  int rn[2][4], cn[2][4];
  if (*flag64) {
    const long long* p = (const long long*)eidx;
#pragma unroll
    for (int m = 0; m < 2; ++m)
#pragma unroll
      for (int r = 0; r < 4; ++r) {
        const int e = ebase + m * 16 + kg * 4 + r;
        rn[m][r] = (int)p[e];
        cn[m][r] = (int)p[NEDGE + e];
      }
  } else {
    const int* p = (const int*)eidx;
#pragma unroll
    for (int m = 0; m < 2; ++m)
#pragma unroll
      for (int r = 0; r < 4; ++r) {
        const int e = ebase + m * 16 + kg * 4 + r;
        rn[m][r] = p[e];
        cn[m][r] = p[NEDGE + e];
      }
  }

  // fill the idx-latency window with independent loads: eattr, W2, b2
  bf16x8 ae0, ae1;
  {
    const float* pe = eattr + (size_t)(ebase + l15) * EDGE_DIM + kg * 8;
    ae0 = pack8(*(const f32x4*)pe, *(const f32x4*)(pe + 4));
  }
  {
    const float* pe = eattr + (size_t)(ebase + 16 + l15) * EDGE_DIM + kg * 8;
    ae1 = pack8(*(const f32x4*)pe, *(const f32x4*)(pe + 4));
  }
  float w2v[NFRAG];
#pragma unroll
  for (int f = 0; f < NFRAG; ++f) w2v[f] = W2[f * 16 + l15];
  const float bias2 = b2[0];

  // P/Q gathers (one dwordx4 per (m,r); 16 in flight)
  u32x4 pu[2][4], qu[2][4];
#pragma unroll
  for (int m = 0; m < 2; ++m)
#pragma unroll
    for (int r = 0; r < 4; ++r)
      pu[m][r] = *(const u32x4*)(Pp + (size_t)rn[m][r] * 64 + l15 * 4);
#pragma unroll
  for (int m = 0; m < 2; ++m)
#pragma unroll
    for (int r = 0; r < 4; ++r)
      qu[m][r] = *(const u32x4*)(Qp + (size_t)cn[m][r] * 64 + l15 * 4);

  // E = eattr @ Wfold (runs while gathers are in flight)
  f32x4 acc[2][NFRAG];
#pragma unroll
  for (int f = 0; f < NFRAG; ++f) {
    bf16x8 bfr = *(const bf16x8*)(Bpack + ((8 * NFRAG + f) * 64 + lane) * 8);
    acc[0][f] = MFMA(ae0, bfr, zero4);
    acc[1][f] = MFMA(ae1, bfr, zero4);
  }

  // accumulate P, then Q (bf16 lo/hi -> f32 via bit ops)
#pragma unroll
  for (int m = 0; m < 2; ++m)
#pragma unroll
    for (int r = 0; r < 4; ++r)
#pragma unroll
      for (int k = 0; k < 4; ++k) {
        const unsigned up = pu[m][r][k];
        acc[m][2 * k][r]     += __builtin_bit_cast(float, up << 16);
        acc[m][2 * k + 1][r] += __builtin_bit_cast(float, up & 0xffff0000u);
      }
#pragma unroll
  for (int m = 0; m < 2; ++m)
#pragma unroll
    for (int r = 0; r < 4; ++r)
#pragma unroll
      for (int k = 0; k < 4; ++k) {
        const unsigned uq = qu[m][r][k];
        acc[m][2 * k][r]     += __builtin_bit_cast(float, uq << 16);
        acc[m][2 * k + 1][r] += __builtin_bit_cast(float, uq & 0xffff0000u);
      }

  // epilogue: relu + dot(W2), 16-lane xor-reduce, sigmoid
  float part[2][4];
#pragma unroll
  for (int m = 0; m < 2; ++m)
#pragma unroll
    for (int rr = 0; rr < 4; ++rr) {
      float s = 0.f;
#pragma unroll
      for (int f = 0; f < NFRAG; ++f) {
        float h = fmaxf(acc[m][f][rr], 0.f);
        s = fmaf(h, w2v[f], s);
      }
      part[m][rr] = s;
    }

#pragma unroll
  for (int mask = 1; mask < 16; mask <<= 1)
#pragma unroll
    for (int m = 0; m < 2; ++m)
#pragma unroll
      for (int rr = 0; rr < 4; ++rr)
        part[m][rr] += __shfl_xor(part[m][rr], mask, 64);

  if (l15 == 0) {
#pragma unroll
    for (int m = 0; m < 2; ++m)
#pragma unroll
      for (int rr = 0; rr < 4; ++rr) {
        float x = part[m][rr] + bias2;
        out[ebase + m * 16 + kg * 4 + rr] = 1.f / (1.f + __expf(-x));
      }
  }
}

// ---- R8 fallback main (bf16 nodes, LDS-staged B)
__global__ __launch_bounds__(512, 4) void edge_attn_kernel(
    const unsigned short* __restrict__ nbf,
    const float* __restrict__ eattr,
    const int*   __restrict__ idx32,
    const unsigned short* __restrict__ Bpack,
    const float* __restrict__ bias_eff,
    const float* __restrict__ W2,
    const float* __restrict__ b2,
    float* __restrict__ out) {
  __shared__ unsigned short lds_b[LDS_KS * NFRAG * 64 * 8];

  const int tid   = threadIdx.x;
  const int lane  = tid & 63;
  const int wid   = tid >> 6;
  const int l15   = lane & 15;
  const int kg    = lane >> 4;
  const int ebase = blockIdx.x * 256 + wid * 32;

#pragma unroll
  for (int i = 0; i < 8; ++i) {
    const char* g = (const char*)Bpack + (size_t)(i * 512 + tid) * 16;
    char*       l = (char*)lds_b + (size_t)(i * 512 + wid * 64) * 16;
    gload_lds16(g, l);
  }

  const int r0 = idx32[ebase + l15];
  const int r1 = idx32[ebase + 16 + l15];
  const int c0 = idx32[NEDGE + ebase + l15];
  const int c1 = idx32[NEDGE + ebase + 16 + l15];

  bf16x8 a0[4], a1[4];
#pragma unroll
  for (int ks = 0; ks < 4; ++ks) {
    a0[ks] = *(const bf16x8*)(nbf + (size_t)r0 * HIDDEN + kg * 8 + ks * 32);
    a1[ks] = *(const bf16x8*)(nbf + (size_t)r1 * HIDDEN + kg * 8 + ks * 32);
  }

  __syncthreads();

  f32x4 acc[2][NFRAG];
#pragma unroll
  for (int m = 0; m < 2; ++m)
#pragma unroll
    for (int f = 0; f < NFRAG; ++f)
      acc[m][f] = (f32x4){0.f, 0.f, 0.f, 0.f};

#pragma unroll
  for (int ks = 0; ks < 4; ++ks)
#pragma unroll
    for (int f = 0; f < NFRAG; ++f) {
      bf16x8 bfr = *(const bf16x8*)(lds_b + ((ks * NFRAG + f) * 64 + lane) * 8);
      acc[0][f] = MFMA(a0[ks], bfr, acc[0][f]);
      acc[1][f] = MFMA(a1[ks], bfr, acc[1][f]);
    }

  __builtin_amdgcn_sched_barrier(0);

#pragma unroll
  for (int ks = 0; ks < 4; ++ks) {
    a0[ks] = *(const bf16x8*)(nbf + (size_t)c0 * HIDDEN + kg * 8 + ks * 32);
    a1[ks] = *(const bf16x8*)(nbf + (size_t)c1 * HIDDEN + kg * 8 + ks * 32);
  }

#pragma unroll
  for (int ks = 0; ks < 4; ++ks)
#pragma unroll
    for (int f = 0; f < NFRAG; ++f) {
      bf16x8 bfr = *(const bf16x8*)(lds_b + (((ks + 4) * NFRAG + f) * 64 + lane) * 8);
      acc[0][f] = MFMA(a0[ks], bfr, acc[0][f]);
      acc[1][f] = MFMA(a1[ks], bfr, acc[1][f]);
    }

  __builtin_amdgcn_sched_barrier(0);

  bf16x8 ae0, ae1;
  {
    const float* pe = eattr + (size_t)(ebase + l15) * EDGE_DIM + kg * 8;
    ae0 = pack8(*(const f32x4*)pe, *(const f32x4*)(pe + 4));
  }
  {
    const float* pe = eattr + (size_t)(ebase + 16 + l15) * EDGE_DIM + kg * 8;
    ae1 = pack8(*(const f32x4*)pe, *(const f32x4*)(pe + 4));
  }
#pragma unroll
  for (int f = 0; f < NFRAG; ++f) {
    bf16x8 bfr = *(const bf16x8*)(Bpack + ((8 * NFRAG + f) * 64 + lane) * 8);
    acc[0][f] = MFMA(ae0, bfr, acc[0][f]);
    acc[1][f] = MFMA(ae1, bfr, acc[1][f]);
  }

  float w2v[NFRAG], bv[NFRAG];
#pragma unroll
  for (int f = 0; f < NFRAG; ++f) {
    w2v[f] = W2[f * 16 + l15];
    bv[f]  = bias_eff[f * 16 + l15];
  }
  const float bias2 = b2[0];

  float part[2][4];
#pragma unroll
  for (int m = 0; m < 2; ++m)
#pragma unroll
    for (int rr = 0; rr < 4; ++rr) {
      float s = 0.f;
#pragma unroll
      for (int f = 0; f < NFRAG; ++f) {
        float h = fmaxf(acc[m][f][rr] + bv[f], 0.f);
        s = fmaf(h, w2v[f], s);
      }
      part[m][rr] = s;
    }

#pragma unroll
  for (int mask = 1; mask < 16; mask <<= 1)
#pragma unroll
    for (int m = 0; m < 2; ++m)
#pragma unroll
      for (int rr = 0; rr < 4; ++rr)
        part[m][rr] += __shfl_xor(part[m][rr], mask, 64);

  if (l15 == 0) {
#pragma unroll
    for (int m = 0; m < 2; ++m)
#pragma unroll
      for (int rr = 0; rr < 4; ++rr) {
        float x = part[m][rr] + bias2;
        out[ebase + m * 16 + kg * 4 + rr] = 1.f / (1.f + __expf(-x));
      }
  }
}

// ---- last-resort fallback (fp32 gathers, global B)
__global__ __launch_bounds__(256) void edge_attn_kernel_fp32(
    const float* __restrict__ nodef,
    const float* __restrict__ eattr,
    const void*  __restrict__ eidx,
    const unsigned short* __restrict__ Bpack,
    const float* __restrict__ bias_eff,
    const float* __restrict__ W2,
    const float* __restrict__ b2,
    const int*   __restrict__ flag64,
    float* __restrict__ out) {
  const int lane  = threadIdx.x & 63;
  const int wid   = threadIdx.x >> 6;
  const int ebase = blockIdx.x * 128 + wid * 32;
  const int l15   = lane & 15;
  const int kg    = lane >> 4;
  const int koff  = kg * 8;
  const int e0 = ebase + l15;
  const int e1 = e0 + 16;

  long r0, c0, r1, c1;
  if (*flag64) {
    const long long* p = (const long long*)eidx;
    r0 = (long)p[e0];          r1 = (long)p[e1];
    c0 = (long)p[NEDGE + e0];  c1 = (long)p[NEDGE + e1];
  } else {
    const int* p = (const int*)eidx;
    r0 = p[e0];          r1 = p[e1];
    c0 = p[NEDGE + e0];  c1 = p[NEDGE + e1];
  }

  f32x4 acc[2][NFRAG];
#pragma unroll
  for (int m = 0; m < 2; ++m)
#pragma unroll
    for (int f = 0; f < NFRAG; ++f)
      acc[m][f] = (f32x4){0.f, 0.f, 0.f, 0.f};

#pragma unroll 1
  for (int ks = 0; ks < KSTEPS; ++ks) {
    const float *p0, *p1;
    if (ks < 4)      { p0 = nodef + r0 * HIDDEN + ks * 32;       p1 = nodef + r1 * HIDDEN + ks * 32; }
    else if (ks < 8) { p0 = nodef + c0 * HIDDEN + (ks - 4) * 32; p1 = nodef + c1 * HIDDEN + (ks - 4) * 32; }
    else             { p0 = eattr + (long)e0 * EDGE_DIM;         p1 = eattr + (long)e1 * EDGE_DIM; }

    f32x4 lo0 = *(const f32x4*)(p0 + koff);
    f32x4 hi0 = *(const f32x4*)(p0 + koff + 4);
    f32x4 lo1 = *(const f32x4*)(p1 + koff);
    f32x4 hi1 = *(const f32x4*)(p1 + koff + 4);
    bf16x8 a0 = pack8(lo0, hi0);
    bf16x8 a1 = pack8(lo1, hi1);

#pragma unroll
    for (int f = 0; f < NFRAG; ++f) {
      bf16x8 bfr = *(const bf16x8*)(Bpack + ((ks * NFRAG + f) * 64 + lane) * 8);
      acc[0][f] = MFMA(a0, bfr, acc[0][f]);
      acc[1][f] = MFMA(a1, bfr, acc[1][f]);
    }
  }

  float w2v[NFRAG], bv[NFRAG];
#pragma unroll
  for (int f = 0; f < NFRAG; ++f) {
    w2v[f] = W2[f * 16 + l15];
    bv[f]  = bias_eff[f * 16 + l15];
  }
  const float bias2 = b2[0];

  float part[2][4];
#pragma unroll
  for (int m = 0; m < 2; ++m)
#pragma unroll
    for (int r = 0; r < 4; ++r) {
      float s = 0.f;
#pragma unroll
      for (int f = 0; f < NFRAG; ++f) {
        float h = acc[m][f][r] + bv[f];
        h = fmaxf(h, 0.f);
        s = fmaf(h, w2v[f], s);
      }
      part[m][r] = s;
    }

#pragma unroll
  for (int mask = 1; mask < 16; mask <<= 1)
#pragma unroll
    for (int m = 0; m < 2; ++m)
#pragma unroll
      for (int r = 0; r < 4; ++r)
        part[m][r] += __shfl_xor(part[m][r], mask, 64);

  if (l15 == 0) {
#pragma unroll
    for (int m = 0; m < 2; ++m)
#pragma unroll
      for (int r = 0; r < 4; ++r) {
        float x = part[m][r] + bias2;
        out[ebase + m * 16 + kg * 4 + r] = 1.f / (1.f + __expf(-x));
      }
  }
}

extern "C" void kernel_launch(void* const* d_in, const int* in_sizes, int n_in,
                              void* d_out, int out_size, void* d_ws, size_t ws_size,
                              hipStream_t stream) {
  const float* nodef  = (const float*)d_in[0];
  const float* eattr  = (const float*)d_in[1];
  const float* W_edge = (const float*)d_in[2];
  const float* b_edge = (const float*)d_in[3];
  const float* W1     = (const float*)d_in[4];
  const float* b1     = (const float*)d_in[5];
  const float* W2     = (const float*)d_in[6];
  const float* b2     = (const float*)d_in[7];
  const void*  eidx   = d_in[8];

  unsigned short* Bpack    = (unsigned short*)d_ws;
  float*          bias_eff = (float*)((char*)d_ws + BIAS_OFF_BYTES);
  int*            flag64   = (int*)((char*)d_ws + FLAG_OFF_BYTES);

  setup_kernel<<<dim3(37), dim3(128), 0, stream>>>(W_edge, b_edge, W1, b1, eidx,
                                                   Bpack, bias_eff, flag64);

  if (ws_size >= (size_t)WS_NEW) {
    unsigned* Pp = (unsigned*)((char*)d_ws + PP_OFF);
    unsigned* Qp = (unsigned*)((char*)d_ws + QP_OFF);
    pq_kernel<<<dim3((NNODE + 255) / 256), dim3(512), 0, stream>>>(nodef, Bpack, bias_eff, Pp, Qp);
    edge_attn_pq<<<dim3(NEDGE / 128), dim3(256), 0, stream>>>(
        eattr, eidx, flag64, Pp, Qp, Bpack, W2, b2, (float*)d_out);
  } else if (ws_size >= (size_t)WS_R8) {
    unsigned short* nbf   = (unsigned short*)((char*)d_ws + NODE_OFF_BYTES);
    int*            idx32 = (int*)((char*)d_ws + IDX_OFF_BYTES);
    cvt_idx_kernel<<<dim3((2 * NEDGE + 255) / 256), dim3(256), 0, stream>>>(eidx, flag64, idx32);
    cvt_nodes_kernel<<<dim3((NNODE * HIDDEN / 8 + 255) / 256), dim3(256), 0, stream>>>(nodef, nbf);
    edge_attn_kernel<<<dim3(NEDGE / 256), dim3(512), 0, stream>>>(
        nbf, eattr, idx32, Bpack, bias_eff, W2, b2, (float*)d_out);
  } else {
    edge_attn_kernel_fp32<<<dim3(NEDGE / 128), dim3(256), 0, stream>>>(
        nodef, eattr, eidx, Bpack, bias_eff, W2, b2, flag64, (float*)d_out);
  }
}

// Round 13
// 140.701 us; speedup vs baseline: 2.3842x; 2.3842x over previous
//
#include <hip/hip_runtime.h>
#include <hip/hip_bf16.h>

#define HIDDEN   128
#define EDGE_DIM 32
#define NNODE    50000
#define NEDGE    800000
#define KSTEPS   9
#define NFRAG    8
#define LDS_KS   8

typedef __attribute__((ext_vector_type(4))) float        f32x4;
typedef __attribute__((ext_vector_type(8))) short        bf16x8;
typedef __attribute__((ext_vector_type(4))) unsigned int u32x4;

#define BPACK_USHORTS  (KSTEPS * NFRAG * 64 * 8)   // 73728 B
#define BIAS_OFF_BYTES (BPACK_USHORTS * 2)
#define FLAG_OFF_BYTES (BIAS_OFF_BYTES + 128 * 4)
#define DATA_OFF       74752

// new-path layout: P/Q packed bf16 (12.8 MB each); no idx buffer needed
#define PP_OFF   DATA_OFF
#define QP_OFF   (PP_OFF + NNODE * HIDDEN * 2)
#define WS_NEW   (QP_OFF + NNODE * HIDDEN * 2)     // ~25.7 MB

// R8-fallback layout
#define NODE_OFF_BYTES DATA_OFF
#define IDX_OFF_BYTES  (NODE_OFF_BYTES + NNODE * HIDDEN * 2)
#define WS_R8          (IDX_OFF_BYTES + 2 * NEDGE * 4)

__device__ __forceinline__ unsigned short f2bf(float f) {
  unsigned u = __builtin_bit_cast(unsigned, f);
  u += 0x7FFFu + ((u >> 16) & 1u);
  return (unsigned short)(u >> 16);
}

__device__ __forceinline__ unsigned cvt_pk_bf16(float a, float b) {
  union { __hip_bfloat162 h; unsigned u; } cv;
  cv.h = __float22bfloat162_rn(make_float2(a, b));   // a -> low16, b -> high16
  return cv.u;
}

__device__ __forceinline__ bf16x8 pack8(f32x4 lo, f32x4 hi) {
  u32x4 u;
  u[0] = cvt_pk_bf16(lo[0], lo[1]);
  u[1] = cvt_pk_bf16(lo[2], lo[3]);
  u[2] = cvt_pk_bf16(hi[0], hi[1]);
  u[3] = cvt_pk_bf16(hi[2], hi[3]);
  return __builtin_bit_cast(bf16x8, u);
}

__device__ __forceinline__ void gload_lds16(const void* g, void* l) {
  __builtin_amdgcn_global_load_lds(
      (const __attribute__((address_space(1))) unsigned int*)g,
      (__attribute__((address_space(3))) unsigned int*)l, 16, 0, 0);
}

#define MFMA(a, b, c) __builtin_amdgcn_mfma_f32_16x16x32_bf16((a), (b), (c), 0, 0, 0)

// ---- setup 1: folded, fragment-packed B + effective bias + idx dtype flag
__global__ void setup_kernel(const float* __restrict__ W_edge,
                             const float* __restrict__ b_edge,
                             const float* __restrict__ W1,
                             const float* __restrict__ b1,
                             const void*  __restrict__ eidx,
                             unsigned short* __restrict__ Bpack,
                             float* __restrict__ bias_eff,
                             int*   __restrict__ flag64) {
  const int bid = blockIdx.x, tid = threadIdx.x;
  if (bid < 36) {
    const int pair  = bid * 2 + (tid >> 6);
    const int lane  = tid & 63;
    const int kstep = pair >> 3;
    const int f     = pair & 7;
    const int col   = f * 16 + (lane & 15);
    const int kbase = kstep * 32 + (lane >> 4) * 8;
    float vals[8];
#pragma unroll
    for (int j = 0; j < 8; ++j) {
      const int k = kbase + j;
      float val;
      if (k < 128) {
        val = W1[k * 128 + col];
      } else if (k < 256) {
        val = W1[(k + 128) * 128 + col];
      } else {
        const int kk = k - 256;
        float s = 0.f;
        for (int t = 0; t < 128; ++t)
          s = fmaf(W_edge[kk * 128 + t], W1[(128 + t) * 128 + col], s);
        val = s;
      }
      vals[j] = val;
    }
    u32x4 sv;
#pragma unroll
    for (int j = 0; j < 4; ++j)
      sv[j] = (unsigned)f2bf(vals[2 * j]) | ((unsigned)f2bf(vals[2 * j + 1]) << 16);
    *(u32x4*)(Bpack + ((kstep * NFRAG + f) * 64 + lane) * 8) = sv;
  } else {
    if (tid < 128) {
      float s = b1[tid];
      for (int t = 0; t < 128; ++t)
        s = fmaf(b_edge[t], W1[(128 + t) * 128 + tid], s);
      bias_eff[tid] = s;
    }
    if (tid == 0) {
      const unsigned* w = (const unsigned*)eidx;
      int all0 = 1;
      for (int i = 0; i < 64; ++i) all0 &= (w[2 * i + 1] == 0u) ? 1 : 0;
      *flag64 = all0;
    }
  }
}

// ---- setup 2 (R8 path only): node_features fp32 -> bf16
__global__ __launch_bounds__(256) void cvt_nodes_kernel(const float* __restrict__ nodef,
                                                        unsigned short* __restrict__ nbf) {
  const int i = blockIdx.x * 256 + threadIdx.x;
  if (i >= NNODE * HIDDEN / 8) return;
  f32x4 lo = *(const f32x4*)(nodef + i * 8);
  f32x4 hi = *(const f32x4*)(nodef + i * 8 + 4);
  *(bf16x8*)(nbf + i * 8) = pack8(lo, hi);
}

// ---- setup 3 (R8 path only): edge_index -> int32
__global__ __launch_bounds__(256) void cvt_idx_kernel(const void* __restrict__ eidx,
                                                      const int* __restrict__ flag64,
                                                      int* __restrict__ idx32) {
  const int i = blockIdx.x * 256 + threadIdx.x;
  if (i >= 2 * NEDGE) return;
  if (*flag64) idx32[i] = (int)((const long long*)eidx)[i];
  else         idx32[i] = ((const int*)eidx)[i];
}

// ---- setup 4: P = nodef@W1a + b1_eff, Q = nodef@W1c, packed bf16.
// TRANSPOSED row layout: dword d = l15*4 + k of node n holds features
// (32k+l15 | 32k+16+l15). One dwordx4 per (node, l15) covers k=0..3.
__global__ __launch_bounds__(512, 2) void pq_kernel(
    const float* __restrict__ nodef,
    const unsigned short* __restrict__ Bpack,
    const float* __restrict__ bias_eff,
    unsigned* __restrict__ Pp,
    unsigned* __restrict__ Qp) {
  __shared__ unsigned short lds_b[LDS_KS * NFRAG * 64 * 8];   // 65536 B

  const int tid  = threadIdx.x;
  const int lane = tid & 63;
  const int wid  = tid >> 6;
  const int l15  = lane & 15;
  const int kg   = lane >> 4;
  const int nb   = blockIdx.x * 256 + wid * 32;

#pragma unroll
  for (int i = 0; i < 8; ++i) {
    const char* g = (const char*)Bpack + (size_t)(i * 512 + tid) * 16;
    char*       l = (char*)lds_b + (size_t)(i * 512 + wid * 64) * 16;
    gload_lds16(g, l);
  }

  const int n0 = min(nb + l15, NNODE - 1);
  const int n1 = min(nb + 16 + l15, NNODE - 1);
  bf16x8 a0[4], a1[4];
#pragma unroll
  for (int ks = 0; ks < 4; ++ks) {
    const float* p0 = nodef + (size_t)n0 * HIDDEN + ks * 32 + kg * 8;
    const float* p1 = nodef + (size_t)n1 * HIDDEN + ks * 32 + kg * 8;
    a0[ks] = pack8(*(const f32x4*)p0, *(const f32x4*)(p0 + 4));
    a1[ks] = pack8(*(const f32x4*)p1, *(const f32x4*)(p1 + 4));
  }

  float bv[NFRAG];
#pragma unroll
  for (int f = 0; f < NFRAG; ++f) bv[f] = bias_eff[f * 16 + l15];

  __syncthreads();

  // P pass (W1a = ks 0..3), bias folded
  f32x4 acc[2][NFRAG];
#pragma unroll
  for (int m = 0; m < 2; ++m)
#pragma unroll
    for (int f = 0; f < NFRAG; ++f)
      acc[m][f] = (f32x4){bv[f], bv[f], bv[f], bv[f]};
#pragma unroll
  for (int ks = 0; ks < 4; ++ks)
#pragma unroll
    for (int f = 0; f < NFRAG; ++f) {
      bf16x8 bfr = *(const bf16x8*)(lds_b + ((ks * NFRAG + f) * 64 + lane) * 8);
      acc[0][f] = MFMA(a0[ks], bfr, acc[0][f]);
      acc[1][f] = MFMA(a1[ks], bfr, acc[1][f]);
    }
#pragma unroll
  for (int m = 0; m < 2; ++m)
#pragma unroll
    for (int r = 0; r < 4; ++r) {
      const int n = nb + m * 16 + kg * 4 + r;
      if (n < NNODE) {
        u32x4 sv;
#pragma unroll
        for (int k = 0; k < 4; ++k)
          sv[k] = cvt_pk_bf16(acc[m][2 * k][r], acc[m][2 * k + 1][r]);
        *(u32x4*)(Pp + (size_t)n * 64 + l15 * 4) = sv;
      }
    }

  // Q pass (W1c = ks 4..7)
#pragma unroll
  for (int m = 0; m < 2; ++m)
#pragma unroll
    for (int f = 0; f < NFRAG; ++f)
      acc[m][f] = (f32x4){0.f, 0.f, 0.f, 0.f};
#pragma unroll
  for (int ks = 0; ks < 4; ++ks)
#pragma unroll
    for (int f = 0; f < NFRAG; ++f) {
      bf16x8 bfr = *(const bf16x8*)(lds_b + (((ks + 4) * NFRAG + f) * 64 + lane) * 8);
      acc[0][f] = MFMA(a0[ks], bfr, acc[0][f]);
      acc[1][f] = MFMA(a1[ks], bfr, acc[1][f]);
    }
#pragma unroll
  for (int m = 0; m < 2; ++m)
#pragma unroll
    for (int r = 0; r < 4; ++r) {
      const int n = nb + m * 16 + kg * 4 + r;
      if (n < NNODE) {
        u32x4 sv;
#pragma unroll
        for (int k = 0; k < 4; ++k)
          sv[k] = cvt_pk_bf16(acc[m][2 * k][r], acc[m][2 * k + 1][r]);
        *(u32x4*)(Qp + (size_t)n * 64 + l15 * 4) = sv;
      }
    }
}

// ---- main: 256 thr = 4 waves x 32 edges, grid 6250, 4 blocks/CU
// (128-reg cap: known-fit for the ~72-100 regs the allocator wants).
// No LDS, no barriers. Reads edge_index directly (uniform dtype branch).
__global__ __launch_bounds__(256, 4) void edge_attn_pq(
    const float* __restrict__ eattr,
    const void*  __restrict__ eidx,
    const int*   __restrict__ flag64,
    const unsigned* __restrict__ Pp,
    const unsigned* __restrict__ Qp,
    const unsigned short* __restrict__ Bpack,
    const float* __restrict__ W2,
    const float* __restrict__ b2,
    float* __restrict__ out) {
  const int tid   = threadIdx.x;
  const int lane  = tid & 63;
  const int wid   = tid >> 6;
  const int l15   = lane & 15;
  const int kg    = lane >> 4;
  const int ebase = blockIdx.x * 128 + wid * 32;

  const f32x4 zero4 = {0.f, 0.f, 0.f, 0.f};

  // indices first (critical path), C-layout rows: edge = ebase + m*16 + kg*4 + r
  int rn[2][4], cn[2][4];
  if (*flag64) {
    const long long* p = (const long long*)eidx;
#pragma unroll
    for (int m = 0; m < 2; ++m)
#pragma unroll
      for (int r = 0; r < 4; ++r) {
        const int e = ebase + m * 16 + kg * 4 + r;
        rn[m][r] = (int)p[e];
        cn[m][r] = (int)p[NEDGE + e];
      }
  } else {
    const int* p = (const int*)eidx;
#pragma unroll
    for (int m = 0; m < 2; ++m)
#pragma unroll
      for (int r = 0; r < 4; ++r) {
        const int e = ebase + m * 16 + kg * 4 + r;
        rn[m][r] = p[e];
        cn[m][r] = p[NEDGE + e];
      }
  }

  // fill the idx-latency window with independent loads: eattr, W2, b2
  bf16x8 ae0, ae1;
  {
    const float* pe = eattr + (size_t)(ebase + l15) * EDGE_DIM + kg * 8;
    ae0 = pack8(*(const f32x4*)pe, *(const f32x4*)(pe + 4));
  }
  {
    const float* pe = eattr + (size_t)(ebase + 16 + l15) * EDGE_DIM + kg * 8;
    ae1 = pack8(*(const f32x4*)pe, *(const f32x4*)(pe + 4));
  }
  float w2v[NFRAG];
#pragma unroll
  for (int f = 0; f < NFRAG; ++f) w2v[f] = W2[f * 16 + l15];
  const float bias2 = b2[0];

  // P/Q gathers (one dwordx4 per (m,r))
  u32x4 pu[2][4], qu[2][4];
#pragma unroll
  for (int m = 0; m < 2; ++m)
#pragma unroll
    for (int r = 0; r < 4; ++r)
      pu[m][r] = *(const u32x4*)(Pp + (size_t)rn[m][r] * 64 + l15 * 4);
#pragma unroll
  for (int m = 0; m < 2; ++m)
#pragma unroll
    for (int r = 0; r < 4; ++r)
      qu[m][r] = *(const u32x4*)(Qp + (size_t)cn[m][r] * 64 + l15 * 4);

  // E = eattr @ Wfold (runs while gathers are in flight)
  f32x4 acc[2][NFRAG];
#pragma unroll
  for (int f = 0; f < NFRAG; ++f) {
    bf16x8 bfr = *(const bf16x8*)(Bpack + ((8 * NFRAG + f) * 64 + lane) * 8);
    acc[0][f] = MFMA(ae0, bfr, zero4);
    acc[1][f] = MFMA(ae1, bfr, zero4);
  }

  // accumulate P, then Q (bf16 lo/hi -> f32 via bit ops)
#pragma unroll
  for (int m = 0; m < 2; ++m)
#pragma unroll
    for (int r = 0; r < 4; ++r)
#pragma unroll
      for (int k = 0; k < 4; ++k) {
        const unsigned up = pu[m][r][k];
        acc[m][2 * k][r]     += __builtin_bit_cast(float, up << 16);
        acc[m][2 * k + 1][r] += __builtin_bit_cast(float, up & 0xffff0000u);
      }
#pragma unroll
  for (int m = 0; m < 2; ++m)
#pragma unroll
    for (int r = 0; r < 4; ++r)
#pragma unroll
      for (int k = 0; k < 4; ++k) {
        const unsigned uq = qu[m][r][k];
        acc[m][2 * k][r]     += __builtin_bit_cast(float, uq << 16);
        acc[m][2 * k + 1][r] += __builtin_bit_cast(float, uq & 0xffff0000u);
      }

  // epilogue: relu + dot(W2), 16-lane xor-reduce, sigmoid
  float part[2][4];
#pragma unroll
  for (int m = 0; m < 2; ++m)
#pragma unroll
    for (int rr = 0; rr < 4; ++rr) {
      float s = 0.f;
#pragma unroll
      for (int f = 0; f < NFRAG; ++f) {
        float h = fmaxf(acc[m][f][rr], 0.f);
        s = fmaf(h, w2v[f], s);
      }
      part[m][rr] = s;
    }

#pragma unroll
  for (int mask = 1; mask < 16; mask <<= 1)
#pragma unroll
    for (int m = 0; m < 2; ++m)
#pragma unroll
      for (int rr = 0; rr < 4; ++rr)
        part[m][rr] += __shfl_xor(part[m][rr], mask, 64);

  if (l15 == 0) {
#pragma unroll
    for (int m = 0; m < 2; ++m)
#pragma unroll
      for (int rr = 0; rr < 4; ++rr) {
        float x = part[m][rr] + bias2;
        out[ebase + m * 16 + kg * 4 + rr] = 1.f / (1.f + __expf(-x));
      }
  }
}

// ---- R8 fallback main (bf16 nodes, LDS-staged B)
__global__ __launch_bounds__(512, 4) void edge_attn_kernel(
    const unsigned short* __restrict__ nbf,
    const float* __restrict__ eattr,
    const int*   __restrict__ idx32,
    const unsigned short* __restrict__ Bpack,
    const float* __restrict__ bias_eff,
    const float* __restrict__ W2,
    const float* __restrict__ b2,
    float* __restrict__ out) {
  __shared__ unsigned short lds_b[LDS_KS * NFRAG * 64 * 8];

  const int tid   = threadIdx.x;
  const int lane  = tid & 63;
  const int wid   = tid >> 6;
  const int l15   = lane & 15;
  const int kg    = lane >> 4;
  const int ebase = blockIdx.x * 256 + wid * 32;

#pragma unroll
  for (int i = 0; i < 8; ++i) {
    const char* g = (const char*)Bpack + (size_t)(i * 512 + tid) * 16;
    char*       l = (char*)lds_b + (size_t)(i * 512 + wid * 64) * 16;
    gload_lds16(g, l);
  }

  const int r0 = idx32[ebase + l15];
  const int r1 = idx32[ebase + 16 + l15];
  const int c0 = idx32[NEDGE + ebase + l15];
  const int c1 = idx32[NEDGE + ebase + 16 + l15];

  bf16x8 a0[4], a1[4];
#pragma unroll
  for (int ks = 0; ks < 4; ++ks) {
    a0[ks] = *(const bf16x8*)(nbf + (size_t)r0 * HIDDEN + kg * 8 + ks * 32);
    a1[ks] = *(const bf16x8*)(nbf + (size_t)r1 * HIDDEN + kg * 8 + ks * 32);
  }

  __syncthreads();

  f32x4 acc[2][NFRAG];
#pragma unroll
  for (int m = 0; m < 2; ++m)
#pragma unroll
    for (int f = 0; f < NFRAG; ++f)
      acc[m][f] = (f32x4){0.f, 0.f, 0.f, 0.f};

#pragma unroll
  for (int ks = 0; ks < 4; ++ks)
#pragma unroll
    for (int f = 0; f < NFRAG; ++f) {
      bf16x8 bfr = *(const bf16x8*)(lds_b + ((ks * NFRAG + f) * 64 + lane) * 8);
      acc[0][f] = MFMA(a0[ks], bfr, acc[0][f]);
      acc[1][f] = MFMA(a1[ks], bfr, acc[1][f]);
    }

  __builtin_amdgcn_sched_barrier(0);

#pragma unroll
  for (int ks = 0; ks < 4; ++ks) {
    a0[ks] = *(const bf16x8*)(nbf + (size_t)c0 * HIDDEN + kg * 8 + ks * 32);
    a1[ks] = *(const bf16x8*)(nbf + (size_t)c1 * HIDDEN + kg * 8 + ks * 32);
  }

#pragma unroll
  for (int ks = 0; ks < 4; ++ks)
#pragma unroll
    for (int f = 0; f < NFRAG; ++f) {
      bf16x8 bfr = *(const bf16x8*)(lds_b + (((ks + 4) * NFRAG + f) * 64 + lane) * 8);
      acc[0][f] = MFMA(a0[ks], bfr, acc[0][f]);
      acc[1][f] = MFMA(a1[ks], bfr, acc[1][f]);
    }

  __builtin_amdgcn_sched_barrier(0);

  bf16x8 ae0, ae1;
  {
    const float* pe = eattr + (size_t)(ebase + l15) * EDGE_DIM + kg * 8;
    ae0 = pack8(*(const f32x4*)pe, *(const f32x4*)(pe + 4));
  }
  {
    const float* pe = eattr + (size_t)(ebase + 16 + l15) * EDGE_DIM + kg * 8;
    ae1 = pack8(*(const f32x4*)pe, *(const f32x4*)(pe + 4));
  }
#pragma unroll
  for (int f = 0; f < NFRAG; ++f) {
    bf16x8 bfr = *(const bf16x8*)(Bpack + ((8 * NFRAG + f) * 64 + lane) * 8);
    acc[0][f] = MFMA(ae0, bfr, acc[0][f]);
    acc[1][f] = MFMA(ae1, bfr, acc[1][f]);
  }

  float w2v[NFRAG], bv[NFRAG];
#pragma unroll
  for (int f = 0; f < NFRAG; ++f) {
    w2v[f] = W2[f * 16 + l15];
    bv[f]  = bias_eff[f * 16 + l15];
  }
  const float bias2 = b2[0];

  float part[2][4];
#pragma unroll
  for (int m = 0; m < 2; ++m)
#pragma unroll
    for (int rr = 0; rr < 4; ++rr) {
      float s = 0.f;
#pragma unroll
      for (int f = 0; f < NFRAG; ++f) {
        float h = fmaxf(acc[m][f][rr] + bv[f], 0.f);
        s = fmaf(h, w2v[f], s);
      }
      part[m][rr] = s;
    }

#pragma unroll
  for (int mask = 1; mask < 16; mask <<= 1)
#pragma unroll
    for (int m = 0; m < 2; ++m)
#pragma unroll
      for (int rr = 0; rr < 4; ++rr)
        part[m][rr] += __shfl_xor(part[m][rr], mask, 64);

  if (l15 == 0) {
#pragma unroll
    for (int m = 0; m < 2; ++m)
#pragma unroll
      for (int rr = 0; rr < 4; ++rr) {
        float x = part[m][rr] + bias2;
        out[ebase + m * 16 + kg * 4 + rr] = 1.f / (1.f + __expf(-x));
      }
  }
}

// ---- last-resort fallback (fp32 gathers, global B)
__global__ __launch_bounds__(256) void edge_attn_kernel_fp32(
    const float* __restrict__ nodef,
    const float* __restrict__ eattr,
    const void*  __restrict__ eidx,
    const unsigned short* __restrict__ Bpack,
    const float* __restrict__ bias_eff,
    const float* __restrict__ W2,
    const float* __restrict__ b2,
    const int*   __restrict__ flag64,
    float* __restrict__ out) {
  const int lane  = threadIdx.x & 63;
  const int wid   = threadIdx.x >> 6;
  const int ebase = blockIdx.x * 128 + wid * 32;
  const int l15   = lane & 15;
  const int kg    = lane >> 4;
  const int koff  = kg * 8;
  const int e0 = ebase + l15;
  const int e1 = e0 + 16;

  long r0, c0, r1, c1;
  if (*flag64) {
    const long long* p = (const long long*)eidx;
    r0 = (long)p[e0];          r1 = (long)p[e1];
    c0 = (long)p[NEDGE + e0];  c1 = (long)p[NEDGE + e1];
  } else {
    const int* p = (const int*)eidx;
    r0 = p[e0];          r1 = p[e1];
    c0 = p[NEDGE + e0];  c1 = p[NEDGE + e1];
  }

  f32x4 acc[2][NFRAG];
#pragma unroll
  for (int m = 0; m < 2; ++m)
#pragma unroll
    for (int f = 0; f < NFRAG; ++f)
      acc[m][f] = (f32x4){0.f, 0.f, 0.f, 0.f};

#pragma unroll 1
  for (int ks = 0; ks < KSTEPS; ++ks) {
    const float *p0, *p1;
    if (ks < 4)      { p0 = nodef + r0 * HIDDEN + ks * 32;       p1 = nodef + r1 * HIDDEN + ks * 32; }
    else if (ks < 8) { p0 = nodef + c0 * HIDDEN + (ks - 4) * 32; p1 = nodef + c1 * HIDDEN + (ks - 4) * 32; }
    else             { p0 = eattr + (long)e0 * EDGE_DIM;         p1 = eattr + (long)e1 * EDGE_DIM; }

    f32x4 lo0 = *(const f32x4*)(p0 + koff);
    f32x4 hi0 = *(const f32x4*)(p0 + koff + 4);
    f32x4 lo1 = *(const f32x4*)(p1 + koff);
    f32x4 hi1 = *(const f32x4*)(p1 + koff + 4);
    bf16x8 a0 = pack8(lo0, hi0);
    bf16x8 a1 = pack8(lo1, hi1);

#pragma unroll
    for (int f = 0; f < NFRAG; ++f) {
      bf16x8 bfr = *(const bf16x8*)(Bpack + ((ks * NFRAG + f) * 64 + lane) * 8);
      acc[0][f] = MFMA(a0, bfr, acc[0][f]);
      acc[1][f] = MFMA(a1, bfr, acc[1][f]);
    }
  }

  float w2v[NFRAG], bv[NFRAG];
#pragma unroll
  for (int f = 0; f < NFRAG; ++f) {
    w2v[f] = W2[f * 16 + l15];
    bv[f]  = bias_eff[f * 16 + l15];
  }
  const float bias2 = b2[0];

  float part[2][4];
#pragma unroll
  for (int m = 0; m < 2; ++m)
#pragma unroll
    for (int r = 0; r < 4; ++r) {
      float s = 0.f;
#pragma unroll
      for (int f = 0; f < NFRAG; ++f) {
        float h = acc[m][f][r] + bv[f];
        h = fmaxf(h, 0.f);
        s = fmaf(h, w2v[f], s);
      }
      part[m][r] = s;
    }

#pragma unroll
  for (int mask = 1; mask < 16; mask <<= 1)
#pragma unroll
    for (int m = 0; m < 2; ++m)
#pragma unroll
      for (int r = 0; r < 4; ++r)
        part[m][r] += __shfl_xor(part[m][r], mask, 64);

  if (l15 == 0) {
#pragma unroll
    for (int m = 0; m < 2; ++m)
#pragma unroll
      for (int r = 0; r < 4; ++r) {
        float x = part[m][r] + bias2;
        out[ebase + m * 16 + kg * 4 + r] = 1.f / (1.f + __expf(-x));
      }
  }
}

extern "C" void kernel_launch(void* const* d_in, const int* in_sizes, int n_in,
                              void* d_out, int out_size, void* d_ws, size_t ws_size,
                              hipStream_t stream) {
  const float* nodef  = (const float*)d_in[0];
  const float* eattr  = (const float*)d_in[1];
  const float* W_edge = (const float*)d_in[2];
  const float* b_edge = (const float*)d_in[3];
  const float* W1     = (const float*)d_in[4];
  const float* b1     = (const float*)d_in[5];
  const float* W2     = (const float*)d_in[6];
  const float* b2     = (const float*)d_in[7];
  const void*  eidx   = d_in[8];

  unsigned short* Bpack    = (unsigned short*)d_ws;
  float*          bias_eff = (float*)((char*)d_ws + BIAS_OFF_BYTES);
  int*            flag64   = (int*)((char*)d_ws + FLAG_OFF_BYTES);

  setup_kernel<<<dim3(37), dim3(128), 0, stream>>>(W_edge, b_edge, W1, b1, eidx,
                                                   Bpack, bias_eff, flag64);

  if (ws_size >= (size_t)WS_NEW) {
    unsigned* Pp = (unsigned*)((char*)d_ws + PP_OFF);
    unsigned* Qp = (unsigned*)((char*)d_ws + QP_OFF);
    pq_kernel<<<dim3((NNODE + 255) / 256), dim3(512), 0, stream>>>(nodef, Bpack, bias_eff, Pp, Qp);
    edge_attn_pq<<<dim3(NEDGE / 128), dim3(256), 0, stream>>>(
        eattr, eidx, flag64, Pp, Qp, Bpack, W2, b2, (float*)d_out);
  } else if (ws_size >= (size_t)WS_R8) {
    unsigned short* nbf   = (unsigned short*)((char*)d_ws + NODE_OFF_BYTES);
    int*            idx32 = (int*)((char*)d_ws + IDX_OFF_BYTES);
    cvt_idx_kernel<<<dim3((2 * NEDGE + 255) / 256), dim3(256), 0, stream>>>(eidx, flag64, idx32);
    cvt_nodes_kernel<<<dim3((NNODE * HIDDEN / 8 + 255) / 256), dim3(256), 0, stream>>>(nodef, nbf);
    edge_attn_kernel<<<dim3(NEDGE / 256), dim3(512), 0, stream>>>(
        nbf, eattr, idx32, Bpack, bias_eff, W2, b2, (float*)d_out);
  } else {
    edge_attn_kernel_fp32<<<dim3(NEDGE / 128), dim3(256), 0, stream>>>(
        nodef, eattr, eidx, Bpack, bias_eff, W2, b2, flag64, (float*)d_out);
  }
}

// Round 14
// 122.707 us; speedup vs baseline: 2.7338x; 1.1466x over previous
//
#include <hip/hip_runtime.h>
#include <hip/hip_bf16.h>

#define HIDDEN   128
#define EDGE_DIM 32
#define NNODE    50000
#define NEDGE    800000
#define KSTEPS   9
#define NFRAG    8
#define LDS_KS   8

typedef __attribute__((ext_vector_type(4))) float        f32x4;
typedef __attribute__((ext_vector_type(8))) short        bf16x8;
typedef __attribute__((ext_vector_type(4))) unsigned int u32x4;

#define BPACK_USHORTS  (KSTEPS * NFRAG * 64 * 8)   // 73728 B
#define BIAS_OFF_BYTES (BPACK_USHORTS * 2)
#define FLAG_OFF_BYTES (BIAS_OFF_BYTES + 128 * 4)
#define DATA_OFF       74752

// new-path layout: P/Q packed bf16 (12.8 MB each)
#define PP_OFF   DATA_OFF
#define QP_OFF   (PP_OFF + NNODE * HIDDEN * 2)
#define WS_NEW   (QP_OFF + NNODE * HIDDEN * 2)     // ~25.7 MB

// R8-fallback layout
#define NODE_OFF_BYTES DATA_OFF
#define IDX_OFF_BYTES  (NODE_OFF_BYTES + NNODE * HIDDEN * 2)
#define WS_R8          (IDX_OFF_BYTES + 2 * NEDGE * 4)

__device__ __forceinline__ unsigned short f2bf(float f) {
  unsigned u = __builtin_bit_cast(unsigned, f);
  u += 0x7FFFu + ((u >> 16) & 1u);
  return (unsigned short)(u >> 16);
}

__device__ __forceinline__ unsigned cvt_pk_bf16(float a, float b) {
  union { __hip_bfloat162 h; unsigned u; } cv;
  cv.h = __float22bfloat162_rn(make_float2(a, b));   // a -> low16, b -> high16
  return cv.u;
}

__device__ __forceinline__ bf16x8 pack8(f32x4 lo, f32x4 hi) {
  u32x4 u;
  u[0] = cvt_pk_bf16(lo[0], lo[1]);
  u[1] = cvt_pk_bf16(lo[2], lo[3]);
  u[2] = cvt_pk_bf16(hi[0], hi[1]);
  u[3] = cvt_pk_bf16(hi[2], hi[3]);
  return __builtin_bit_cast(bf16x8, u);
}

__device__ __forceinline__ void gload_lds16(const void* g, void* l) {
  __builtin_amdgcn_global_load_lds(
      (const __attribute__((address_space(1))) unsigned int*)g,
      (__attribute__((address_space(3))) unsigned int*)l, 16, 0, 0);
}

#define MFMA(a, b, c) __builtin_amdgcn_mfma_f32_16x16x32_bf16((a), (b), (c), 0, 0, 0)

// ---- setup 1: folded, fragment-packed B + effective bias + idx dtype flag
__global__ void setup_kernel(const float* __restrict__ W_edge,
                             const float* __restrict__ b_edge,
                             const float* __restrict__ W1,
                             const float* __restrict__ b1,
                             const void*  __restrict__ eidx,
                             unsigned short* __restrict__ Bpack,
                             float* __restrict__ bias_eff,
                             int*   __restrict__ flag64) {
  const int bid = blockIdx.x, tid = threadIdx.x;
  if (bid < 36) {
    const int pair  = bid * 2 + (tid >> 6);
    const int lane  = tid & 63;
    const int kstep = pair >> 3;
    const int f     = pair & 7;
    const int col   = f * 16 + (lane & 15);
    const int kbase = kstep * 32 + (lane >> 4) * 8;
    float vals[8];
#pragma unroll
    for (int j = 0; j < 8; ++j) {
      const int k = kbase + j;
      float val;
      if (k < 128) {
        val = W1[k * 128 + col];
      } else if (k < 256) {
        val = W1[(k + 128) * 128 + col];
      } else {
        const int kk = k - 256;
        float s = 0.f;
        for (int t = 0; t < 128; ++t)
          s = fmaf(W_edge[kk * 128 + t], W1[(128 + t) * 128 + col], s);
        val = s;
      }
      vals[j] = val;
    }
    u32x4 sv;
#pragma unroll
    for (int j = 0; j < 4; ++j)
      sv[j] = (unsigned)f2bf(vals[2 * j]) | ((unsigned)f2bf(vals[2 * j + 1]) << 16);
    *(u32x4*)(Bpack + ((kstep * NFRAG + f) * 64 + lane) * 8) = sv;
  } else {
    if (tid < 128) {
      float s = b1[tid];
      for (int t = 0; t < 128; ++t)
        s = fmaf(b_edge[t], W1[(128 + t) * 128 + tid], s);
      bias_eff[tid] = s;
    }
    if (tid == 0) {
      const unsigned* w = (const unsigned*)eidx;
      int all0 = 1;
      for (int i = 0; i < 64; ++i) all0 &= (w[2 * i + 1] == 0u) ? 1 : 0;
      *flag64 = all0;
    }
  }
}

// ---- setup 2 (R8 path only): node_features fp32 -> bf16
__global__ __launch_bounds__(256) void cvt_nodes_kernel(const float* __restrict__ nodef,
                                                        unsigned short* __restrict__ nbf) {
  const int i = blockIdx.x * 256 + threadIdx.x;
  if (i >= NNODE * HIDDEN / 8) return;
  f32x4 lo = *(const f32x4*)(nodef + i * 8);
  f32x4 hi = *(const f32x4*)(nodef + i * 8 + 4);
  *(bf16x8*)(nbf + i * 8) = pack8(lo, hi);
}

// ---- setup 3 (R8 path only): edge_index -> int32
__global__ __launch_bounds__(256) void cvt_idx_kernel(const void* __restrict__ eidx,
                                                      const int* __restrict__ flag64,
                                                      int* __restrict__ idx32) {
  const int i = blockIdx.x * 256 + threadIdx.x;
  if (i >= 2 * NEDGE) return;
  if (*flag64) idx32[i] = (int)((const long long*)eidx)[i];
  else         idx32[i] = ((const int*)eidx)[i];
}

// ---- setup 4: P = nodef@W1a + b1_eff, Q = nodef@W1c, packed bf16.
// TRANSPOSED row layout: dword d = l15*4 + k of node n holds features
// (32k+l15 | 32k+16+l15). One dwordx4 per (node, l15) covers k=0..3.
__global__ __launch_bounds__(512, 2) void pq_kernel(
    const float* __restrict__ nodef,
    const unsigned short* __restrict__ Bpack,
    const float* __restrict__ bias_eff,
    unsigned* __restrict__ Pp,
    unsigned* __restrict__ Qp) {
  __shared__ unsigned short lds_b[LDS_KS * NFRAG * 64 * 8];   // 65536 B

  const int tid  = threadIdx.x;
  const int lane = tid & 63;
  const int wid  = tid >> 6;
  const int l15  = lane & 15;
  const int kg   = lane >> 4;
  const int nb   = blockIdx.x * 256 + wid * 32;

#pragma unroll
  for (int i = 0; i < 8; ++i) {
    const char* g = (const char*)Bpack + (size_t)(i * 512 + tid) * 16;
    char*       l = (char*)lds_b + (size_t)(i * 512 + wid * 64) * 16;
    gload_lds16(g, l);
  }

  const int n0 = min(nb + l15, NNODE - 1);
  const int n1 = min(nb + 16 + l15, NNODE - 1);
  bf16x8 a0[4], a1[4];
#pragma unroll
  for (int ks = 0; ks < 4; ++ks) {
    const float* p0 = nodef + (size_t)n0 * HIDDEN + ks * 32 + kg * 8;
    const float* p1 = nodef + (size_t)n1 * HIDDEN + ks * 32 + kg * 8;
    a0[ks] = pack8(*(const f32x4*)p0, *(const f32x4*)(p0 + 4));
    a1[ks] = pack8(*(const f32x4*)p1, *(const f32x4*)(p1 + 4));
  }

  float bv[NFRAG];
#pragma unroll
  for (int f = 0; f < NFRAG; ++f) bv[f] = bias_eff[f * 16 + l15];

  __syncthreads();

  // P pass (W1a = ks 0..3), bias folded
  f32x4 acc[2][NFRAG];
#pragma unroll
  for (int m = 0; m < 2; ++m)
#pragma unroll
    for (int f = 0; f < NFRAG; ++f)
      acc[m][f] = (f32x4){bv[f], bv[f], bv[f], bv[f]};
#pragma unroll
  for (int ks = 0; ks < 4; ++ks)
#pragma unroll
    for (int f = 0; f < NFRAG; ++f) {
      bf16x8 bfr = *(const bf16x8*)(lds_b + ((ks * NFRAG + f) * 64 + lane) * 8);
      acc[0][f] = MFMA(a0[ks], bfr, acc[0][f]);
      acc[1][f] = MFMA(a1[ks], bfr, acc[1][f]);
    }
#pragma unroll
  for (int m = 0; m < 2; ++m)
#pragma unroll
    for (int r = 0; r < 4; ++r) {
      const int n = nb + m * 16 + kg * 4 + r;
      if (n < NNODE) {
        u32x4 sv;
#pragma unroll
        for (int k = 0; k < 4; ++k)
          sv[k] = cvt_pk_bf16(acc[m][2 * k][r], acc[m][2 * k + 1][r]);
        *(u32x4*)(Pp + (size_t)n * 64 + l15 * 4) = sv;
      }
    }

  // Q pass (W1c = ks 4..7)
#pragma unroll
  for (int m = 0; m < 2; ++m)
#pragma unroll
    for (int f = 0; f < NFRAG; ++f)
      acc[m][f] = (f32x4){0.f, 0.f, 0.f, 0.f};
#pragma unroll
  for (int ks = 0; ks < 4; ++ks)
#pragma unroll
    for (int f = 0; f < NFRAG; ++f) {
      bf16x8 bfr = *(const bf16x8*)(lds_b + (((ks + 4) * NFRAG + f) * 64 + lane) * 8);
      acc[0][f] = MFMA(a0[ks], bfr, acc[0][f]);
      acc[1][f] = MFMA(a1[ks], bfr, acc[1][f]);
    }
#pragma unroll
  for (int m = 0; m < 2; ++m)
#pragma unroll
    for (int r = 0; r < 4; ++r) {
      const int n = nb + m * 16 + kg * 4 + r;
      if (n < NNODE) {
        u32x4 sv;
#pragma unroll
        for (int k = 0; k < 4; ++k)
          sv[k] = cvt_pk_bf16(acc[m][2 * k][r], acc[m][2 * k + 1][r]);
        *(u32x4*)(Qp + (size_t)n * 64 + l15 * 4) = sv;
      }
    }
}

// ---- main: 256 thr = 4 waves x 32 edges, grid 6250, 4 blocks/CU.
// Indices read as LOW DWORD of edge_index with uniform stride (2 for int64,
// 1 for int32) -> int32-class register pressure, no cvt kernel.
__global__ __launch_bounds__(256, 4) void edge_attn_pq(
    const float* __restrict__ eattr,
    const void*  __restrict__ eidx,
    const int*   __restrict__ flag64,
    const unsigned* __restrict__ Pp,
    const unsigned* __restrict__ Qp,
    const unsigned short* __restrict__ Bpack,
    const float* __restrict__ W2,
    const float* __restrict__ b2,
    float* __restrict__ out) {
  const int tid   = threadIdx.x;
  const int lane  = tid & 63;
  const int wid   = tid >> 6;
  const int l15   = lane & 15;
  const int kg    = lane >> 4;
  const int ebase = blockIdx.x * 128 + wid * 32;

  const f32x4 zero4 = {0.f, 0.f, 0.f, 0.f};

  // indices (low dword, uniform stride), C-layout rows:
  // edge = ebase + m*16 + kg*4 + r
  const int s = (*flag64) ? 2 : 1;     // little-endian: low word of int64 at 2*e
  const int* p32 = (const int*)eidx;
  int rn[2][4], cn[2][4];
#pragma unroll
  for (int m = 0; m < 2; ++m)
#pragma unroll
    for (int r = 0; r < 4; ++r) {
      const int e = ebase + m * 16 + kg * 4 + r;
      rn[m][r] = p32[(size_t)e * s];
      cn[m][r] = p32[((size_t)NEDGE + e) * s];
    }

  // fill the idx-latency window with independent loads: eattr, W2, b2
  bf16x8 ae0, ae1;
  {
    const float* pe = eattr + (size_t)(ebase + l15) * EDGE_DIM + kg * 8;
    ae0 = pack8(*(const f32x4*)pe, *(const f32x4*)(pe + 4));
  }
  {
    const float* pe = eattr + (size_t)(ebase + 16 + l15) * EDGE_DIM + kg * 8;
    ae1 = pack8(*(const f32x4*)pe, *(const f32x4*)(pe + 4));
  }
  float w2v[NFRAG];
#pragma unroll
  for (int f = 0; f < NFRAG; ++f) w2v[f] = W2[f * 16 + l15];
  const float bias2 = b2[0];

  // P/Q gathers (one dwordx4 per (m,r))
  u32x4 pu[2][4], qu[2][4];
#pragma unroll
  for (int m = 0; m < 2; ++m)
#pragma unroll
    for (int r = 0; r < 4; ++r)
      pu[m][r] = *(const u32x4*)(Pp + (size_t)rn[m][r] * 64 + l15 * 4);
#pragma unroll
  for (int m = 0; m < 2; ++m)
#pragma unroll
    for (int r = 0; r < 4; ++r)
      qu[m][r] = *(const u32x4*)(Qp + (size_t)cn[m][r] * 64 + l15 * 4);

  // E = eattr @ Wfold (runs while gathers are in flight)
  f32x4 acc[2][NFRAG];
#pragma unroll
  for (int f = 0; f < NFRAG; ++f) {
    bf16x8 bfr = *(const bf16x8*)(Bpack + ((8 * NFRAG + f) * 64 + lane) * 8);
    acc[0][f] = MFMA(ae0, bfr, zero4);
    acc[1][f] = MFMA(ae1, bfr, zero4);
  }

  // accumulate P, then Q (bf16 lo/hi -> f32 via bit ops)
#pragma unroll
  for (int m = 0; m < 2; ++m)
#pragma unroll
    for (int r = 0; r < 4; ++r)
#pragma unroll
      for (int k = 0; k < 4; ++k) {
        const unsigned up = pu[m][r][k];
        acc[m][2 * k][r]     += __builtin_bit_cast(float, up << 16);
        acc[m][2 * k + 1][r] += __builtin_bit_cast(float, up & 0xffff0000u);
      }
#pragma unroll
  for (int m = 0; m < 2; ++m)
#pragma unroll
    for (int r = 0; r < 4; ++r)
#pragma unroll
      for (int k = 0; k < 4; ++k) {
        const unsigned uq = qu[m][r][k];
        acc[m][2 * k][r]     += __builtin_bit_cast(float, uq << 16);
        acc[m][2 * k + 1][r] += __builtin_bit_cast(float, uq & 0xffff0000u);
      }

  // epilogue: relu + dot(W2), 16-lane xor-reduce, sigmoid
  float part[2][4];
#pragma unroll
  for (int m = 0; m < 2; ++m)
#pragma unroll
    for (int rr = 0; rr < 4; ++rr) {
      float s2 = 0.f;
#pragma unroll
      for (int f = 0; f < NFRAG; ++f) {
        float h = fmaxf(acc[m][f][rr], 0.f);
        s2 = fmaf(h, w2v[f], s2);
      }
      part[m][rr] = s2;
    }

#pragma unroll
  for (int mask = 1; mask < 16; mask <<= 1)
#pragma unroll
    for (int m = 0; m < 2; ++m)
#pragma unroll
      for (int rr = 0; rr < 4; ++rr)
        part[m][rr] += __shfl_xor(part[m][rr], mask, 64);

  if (l15 == 0) {
#pragma unroll
    for (int m = 0; m < 2; ++m)
#pragma unroll
      for (int rr = 0; rr < 4; ++rr) {
        float x = part[m][rr] + bias2;
        out[ebase + m * 16 + kg * 4 + rr] = 1.f / (1.f + __expf(-x));
      }
  }
}

// ---- R8 fallback main (bf16 nodes, LDS-staged B)
__global__ __launch_bounds__(512, 4) void edge_attn_kernel(
    const unsigned short* __restrict__ nbf,
    const float* __restrict__ eattr,
    const int*   __restrict__ idx32,
    const unsigned short* __restrict__ Bpack,
    const float* __restrict__ bias_eff,
    const float* __restrict__ W2,
    const float* __restrict__ b2,
    float* __restrict__ out) {
  __shared__ unsigned short lds_b[LDS_KS * NFRAG * 64 * 8];

  const int tid   = threadIdx.x;
  const int lane  = tid & 63;
  const int wid   = tid >> 6;
  const int l15   = lane & 15;
  const int kg    = lane >> 4;
  const int ebase = blockIdx.x * 256 + wid * 32;

#pragma unroll
  for (int i = 0; i < 8; ++i) {
    const char* g = (const char*)Bpack + (size_t)(i * 512 + tid) * 16;
    char*       l = (char*)lds_b + (size_t)(i * 512 + wid * 64) * 16;
    gload_lds16(g, l);
  }

  const int r0 = idx32[ebase + l15];
  const int r1 = idx32[ebase + 16 + l15];
  const int c0 = idx32[NEDGE + ebase + l15];
  const int c1 = idx32[NEDGE + ebase + 16 + l15];

  bf16x8 a0[4], a1[4];
#pragma unroll
  for (int ks = 0; ks < 4; ++ks) {
    a0[ks] = *(const bf16x8*)(nbf + (size_t)r0 * HIDDEN + kg * 8 + ks * 32);
    a1[ks] = *(const bf16x8*)(nbf + (size_t)r1 * HIDDEN + kg * 8 + ks * 32);
  }

  __syncthreads();

  f32x4 acc[2][NFRAG];
#pragma unroll
  for (int m = 0; m < 2; ++m)
#pragma unroll
    for (int f = 0; f < NFRAG; ++f)
      acc[m][f] = (f32x4){0.f, 0.f, 0.f, 0.f};

#pragma unroll
  for (int ks = 0; ks < 4; ++ks)
#pragma unroll
    for (int f = 0; f < NFRAG; ++f) {
      bf16x8 bfr = *(const bf16x8*)(lds_b + ((ks * NFRAG + f) * 64 + lane) * 8);
      acc[0][f] = MFMA(a0[ks], bfr, acc[0][f]);
      acc[1][f] = MFMA(a1[ks], bfr, acc[1][f]);
    }

  __builtin_amdgcn_sched_barrier(0);

#pragma unroll
  for (int ks = 0; ks < 4; ++ks) {
    a0[ks] = *(const bf16x8*)(nbf + (size_t)c0 * HIDDEN + kg * 8 + ks * 32);
    a1[ks] = *(const bf16x8*)(nbf + (size_t)c1 * HIDDEN + kg * 8 + ks * 32);
  }

#pragma unroll
  for (int ks = 0; ks < 4; ++ks)
#pragma unroll
    for (int f = 0; f < NFRAG; ++f) {
      bf16x8 bfr = *(const bf16x8*)(lds_b + (((ks + 4) * NFRAG + f) * 64 + lane) * 8);
      acc[0][f] = MFMA(a0[ks], bfr, acc[0][f]);
      acc[1][f] = MFMA(a1[ks], bfr, acc[1][f]);
    }

  __builtin_amdgcn_sched_barrier(0);

  bf16x8 ae0, ae1;
  {
    const float* pe = eattr + (size_t)(ebase + l15) * EDGE_DIM + kg * 8;
    ae0 = pack8(*(const f32x4*)pe, *(const f32x4*)(pe + 4));
  }
  {
    const float* pe = eattr + (size_t)(ebase + 16 + l15) * EDGE_DIM + kg * 8;
    ae1 = pack8(*(const f32x4*)pe, *(const f32x4*)(pe + 4));
  }
#pragma unroll
  for (int f = 0; f < NFRAG; ++f) {
    bf16x8 bfr = *(const bf16x8*)(Bpack + ((8 * NFRAG + f) * 64 + lane) * 8);
    acc[0][f] = MFMA(ae0, bfr, acc[0][f]);
    acc[1][f] = MFMA(ae1, bfr, acc[1][f]);
  }

  float w2v[NFRAG], bv[NFRAG];
#pragma unroll
  for (int f = 0; f < NFRAG; ++f) {
    w2v[f] = W2[f * 16 + l15];
    bv[f]  = bias_eff[f * 16 + l15];
  }
  const float bias2 = b2[0];

  float part[2][4];
#pragma unroll
  for (int m = 0; m < 2; ++m)
#pragma unroll
    for (int rr = 0; rr < 4; ++rr) {
      float s = 0.f;
#pragma unroll
      for (int f = 0; f < NFRAG; ++f) {
        float h = fmaxf(acc[m][f][rr] + bv[f], 0.f);
        s = fmaf(h, w2v[f], s);
      }
      part[m][rr] = s;
    }

#pragma unroll
  for (int mask = 1; mask < 16; mask <<= 1)
#pragma unroll
    for (int m = 0; m < 2; ++m)
#pragma unroll
      for (int rr = 0; rr < 4; ++rr)
        part[m][rr] += __shfl_xor(part[m][rr], mask, 64);

  if (l15 == 0) {
#pragma unroll
    for (int m = 0; m < 2; ++m)
#pragma unroll
      for (int rr = 0; rr < 4; ++rr) {
        float x = part[m][rr] + bias2;
        out[ebase + m * 16 + kg * 4 + rr] = 1.f / (1.f + __expf(-x));
      }
  }
}

// ---- last-resort fallback (fp32 gathers, global B)
__global__ __launch_bounds__(256) void edge_attn_kernel_fp32(
    const float* __restrict__ nodef,
    const float* __restrict__ eattr,
    const void*  __restrict__ eidx,
    const unsigned short* __restrict__ Bpack,
    const float* __restrict__ bias_eff,
    const float* __restrict__ W2,
    const float* __restrict__ b2,
    const int*   __restrict__ flag64,
    float* __restrict__ out) {
  const int lane  = threadIdx.x & 63;
  const int wid   = threadIdx.x >> 6;
  const int ebase = blockIdx.x * 128 + wid * 32;
  const int l15   = lane & 15;
  const int kg    = lane >> 4;
  const int koff  = kg * 8;
  const int e0 = ebase + l15;
  const int e1 = e0 + 16;

  long r0, c0, r1, c1;
  if (*flag64) {
    const long long* p = (const long long*)eidx;
    r0 = (long)p[e0];          r1 = (long)p[e1];
    c0 = (long)p[NEDGE + e0];  c1 = (long)p[NEDGE + e1];
  } else {
    const int* p = (const int*)eidx;
    r0 = p[e0];          r1 = p[e1];
    c0 = p[NEDGE + e0];  c1 = p[NEDGE + e1];
  }

  f32x4 acc[2][NFRAG];
#pragma unroll
  for (int m = 0; m < 2; ++m)
#pragma unroll
    for (int f = 0; f < NFRAG; ++f)
      acc[m][f] = (f32x4){0.f, 0.f, 0.f, 0.f};

#pragma unroll 1
  for (int ks = 0; ks < KSTEPS; ++ks) {
    const float *p0, *p1;
    if (ks < 4)      { p0 = nodef + r0 * HIDDEN + ks * 32;       p1 = nodef + r1 * HIDDEN + ks * 32; }
    else if (ks < 8) { p0 = nodef + c0 * HIDDEN + (ks - 4) * 32; p1 = nodef + c1 * HIDDEN + (ks - 4) * 32; }
    else             { p0 = eattr + (long)e0 * EDGE_DIM;         p1 = eattr + (long)e1 * EDGE_DIM; }

    f32x4 lo0 = *(const f32x4*)(p0 + koff);
    f32x4 hi0 = *(const f32x4*)(p0 + koff + 4);
    f32x4 lo1 = *(const f32x4*)(p1 + koff);
    f32x4 hi1 = *(const f32x4*)(p1 + koff + 4);
    bf16x8 a0 = pack8(lo0, hi0);
    bf16x8 a1 = pack8(lo1, hi1);

#pragma unroll
    for (int f = 0; f < NFRAG; ++f) {
      bf16x8 bfr = *(const bf16x8*)(Bpack + ((ks * NFRAG + f) * 64 + lane) * 8);
      acc[0][f] = MFMA(a0, bfr, acc[0][f]);
      acc[1][f] = MFMA(a1, bfr, acc[1][f]);
    }
  }

  float w2v[NFRAG], bv[NFRAG];
#pragma unroll
  for (int f = 0; f < NFRAG; ++f) {
    w2v[f] = W2[f * 16 + l15];
    bv[f]  = bias_eff[f * 16 + l15];
  }
  const float bias2 = b2[0];

  float part[2][4];
#pragma unroll
  for (int m = 0; m < 2; ++m)
#pragma unroll
    for (int r = 0; r < 4; ++r) {
      float s = 0.f;
#pragma unroll
      for (int f = 0; f < NFRAG; ++f) {
        float h = acc[m][f][r] + bv[f];
        h = fmaxf(h, 0.f);
        s = fmaf(h, w2v[f], s);
      }
      part[m][r] = s;
    }

#pragma unroll
  for (int mask = 1; mask < 16; mask <<= 1)
#pragma unroll
    for (int m = 0; m < 2; ++m)
#pragma unroll
      for (int r = 0; r < 4; ++r)
        part[m][r] += __shfl_xor(part[m][r], mask, 64);

  if (l15 == 0) {
#pragma unroll
    for (int m = 0; m < 2; ++m)
#pragma unroll
      for (int r = 0; r < 4; ++r) {
        float x = part[m][r] + bias2;
        out[ebase + m * 16 + kg * 4 + r] = 1.f / (1.f + __expf(-x));
      }
  }
}

extern "C" void kernel_launch(void* const* d_in, const int* in_sizes, int n_in,
                              void* d_out, int out_size, void* d_ws, size_t ws_size,
                              hipStream_t stream) {
  const float* nodef  = (const float*)d_in[0];
  const float* eattr  = (const float*)d_in[1];
  const float* W_edge = (const float*)d_in[2];
  const float* b_edge = (const float*)d_in[3];
  const float* W1     = (const float*)d_in[4];
  const float* b1     = (const float*)d_in[5];
  const float* W2     = (const float*)d_in[6];
  const float* b2     = (const float*)d_in[7];
  const void*  eidx   = d_in[8];

  unsigned short* Bpack    = (unsigned short*)d_ws;
  float*          bias_eff = (float*)((char*)d_ws + BIAS_OFF_BYTES);
  int*            flag64   = (int*)((char*)d_ws + FLAG_OFF_BYTES);

  setup_kernel<<<dim3(37), dim3(128), 0, stream>>>(W_edge, b_edge, W1, b1, eidx,
                                                   Bpack, bias_eff, flag64);

  if (ws_size >= (size_t)WS_NEW) {
    unsigned* Pp = (unsigned*)((char*)d_ws + PP_OFF);
    unsigned* Qp = (unsigned*)((char*)d_ws + QP_OFF);
    pq_kernel<<<dim3((NNODE + 255) / 256), dim3(512), 0, stream>>>(nodef, Bpack, bias_eff, Pp, Qp);
    edge_attn_pq<<<dim3(NEDGE / 128), dim3(256), 0, stream>>>(
        eattr, eidx, flag64, Pp, Qp, Bpack, W2, b2, (float*)d_out);
  } else if (ws_size >= (size_t)WS_R8) {
    unsigned short* nbf   = (unsigned short*)((char*)d_ws + NODE_OFF_BYTES);
    int*            idx32 = (int*)((char*)d_ws + IDX_OFF_BYTES);
    cvt_idx_kernel<<<dim3((2 * NEDGE + 255) / 256), dim3(256), 0, stream>>>(eidx, flag64, idx32);
    cvt_nodes_kernel<<<dim3((NNODE * HIDDEN / 8 + 255) / 256), dim3(256), 0, stream>>>(nodef, nbf);
    edge_attn_kernel<<<dim3(NEDGE / 256), dim3(512), 0, stream>>>(
        nbf, eattr, idx32, Bpack, bias_eff, W2, b2, (float*)d_out);
  } else {
    edge_attn_kernel_fp32<<<dim3(NEDGE / 128), dim3(256), 0, stream>>>(
        nodef, eattr, eidx, Bpack, bias_eff, W2, b2, flag64, (float*)d_out);
  }
}

// Round 15
// 106.638 us; speedup vs baseline: 3.1458x; 1.1507x over previous
//
#include <hip/hip_runtime.h>
#include <hip/hip_bf16.h>

#define HIDDEN   128
#define EDGE_DIM 32
#define NNODE    50000
#define NEDGE    800000
#define KSTEPS   9
#define NFRAG    8
#define LDS_KS   8

typedef __attribute__((ext_vector_type(4))) float        f32x4;
typedef __attribute__((ext_vector_type(8))) short        bf16x8;
typedef __attribute__((ext_vector_type(4))) unsigned int u32x4;

#define BPACK_USHORTS  (KSTEPS * NFRAG * 64 * 8)   // 73728 B
#define BIAS_OFF_BYTES (BPACK_USHORTS * 2)
#define FLAG_OFF_BYTES (BIAS_OFF_BYTES + 128 * 4)
#define DATA_OFF       74752

// new-path layout: P/Q packed bf16 (12.8 MB each)
#define PP_OFF   DATA_OFF
#define QP_OFF   (PP_OFF + NNODE * HIDDEN * 2)
#define WS_NEW   (QP_OFF + NNODE * HIDDEN * 2)     // ~25.7 MB

// R8-fallback layout
#define NODE_OFF_BYTES DATA_OFF
#define IDX_OFF_BYTES  (NODE_OFF_BYTES + NNODE * HIDDEN * 2)
#define WS_R8          (IDX_OFF_BYTES + 2 * NEDGE * 4)

__device__ __forceinline__ unsigned short f2bf(float f) {
  unsigned u = __builtin_bit_cast(unsigned, f);
  u += 0x7FFFu + ((u >> 16) & 1u);
  return (unsigned short)(u >> 16);
}

__device__ __forceinline__ unsigned cvt_pk_bf16(float a, float b) {
  union { __hip_bfloat162 h; unsigned u; } cv;
  cv.h = __float22bfloat162_rn(make_float2(a, b));   // a -> low16, b -> high16
  return cv.u;
}

__device__ __forceinline__ bf16x8 pack8(f32x4 lo, f32x4 hi) {
  u32x4 u;
  u[0] = cvt_pk_bf16(lo[0], lo[1]);
  u[1] = cvt_pk_bf16(lo[2], lo[3]);
  u[2] = cvt_pk_bf16(hi[0], hi[1]);
  u[3] = cvt_pk_bf16(hi[2], hi[3]);
  return __builtin_bit_cast(bf16x8, u);
}

__device__ __forceinline__ void gload_lds16(const void* g, void* l) {
  __builtin_amdgcn_global_load_lds(
      (const __attribute__((address_space(1))) unsigned int*)g,
      (__attribute__((address_space(3))) unsigned int*)l, 16, 0, 0);
}

#define MFMA(a, b, c) __builtin_amdgcn_mfma_f32_16x16x32_bf16((a), (b), (c), 0, 0, 0)

// ---- setup 1: folded, fragment-packed B + effective bias + idx dtype flag
__global__ void setup_kernel(const float* __restrict__ W_edge,
                             const float* __restrict__ b_edge,
                             const float* __restrict__ W1,
                             const float* __restrict__ b1,
                             const void*  __restrict__ eidx,
                             unsigned short* __restrict__ Bpack,
                             float* __restrict__ bias_eff,
                             int*   __restrict__ flag64) {
  const int bid = blockIdx.x, tid = threadIdx.x;
  if (bid < 36) {
    const int pair  = bid * 2 + (tid >> 6);
    const int lane  = tid & 63;
    const int kstep = pair >> 3;
    const int f     = pair & 7;
    const int col   = f * 16 + (lane & 15);
    const int kbase = kstep * 32 + (lane >> 4) * 8;
    float vals[8];
#pragma unroll
    for (int j = 0; j < 8; ++j) {
      const int k = kbase + j;
      float val;
      if (k < 128) {
        val = W1[k * 128 + col];
      } else if (k < 256) {
        val = W1[(k + 128) * 128 + col];
      } else {
        const int kk = k - 256;
        float s = 0.f;
        for (int t = 0; t < 128; ++t)
          s = fmaf(W_edge[kk * 128 + t], W1[(128 + t) * 128 + col], s);
        val = s;
      }
      vals[j] = val;
    }
    u32x4 sv;
#pragma unroll
    for (int j = 0; j < 4; ++j)
      sv[j] = (unsigned)f2bf(vals[2 * j]) | ((unsigned)f2bf(vals[2 * j + 1]) << 16);
    *(u32x4*)(Bpack + ((kstep * NFRAG + f) * 64 + lane) * 8) = sv;
  } else {
    if (tid < 128) {
      float s = b1[tid];
      for (int t = 0; t < 128; ++t)
        s = fmaf(b_edge[t], W1[(128 + t) * 128 + tid], s);
      bias_eff[tid] = s;
    }
    if (tid == 0) {
      const unsigned* w = (const unsigned*)eidx;
      int all0 = 1;
      for (int i = 0; i < 64; ++i) all0 &= (w[2 * i + 1] == 0u) ? 1 : 0;
      *flag64 = all0;
    }
  }
}

// ---- setup 2 (R8 path only): node_features fp32 -> bf16
__global__ __launch_bounds__(256) void cvt_nodes_kernel(const float* __restrict__ nodef,
                                                        unsigned short* __restrict__ nbf) {
  const int i = blockIdx.x * 256 + threadIdx.x;
  if (i >= NNODE * HIDDEN / 8) return;
  f32x4 lo = *(const f32x4*)(nodef + i * 8);
  f32x4 hi = *(const f32x4*)(nodef + i * 8 + 4);
  *(bf16x8*)(nbf + i * 8) = pack8(lo, hi);
}

// ---- setup 3 (R8 path only): edge_index -> int32
__global__ __launch_bounds__(256) void cvt_idx_kernel(const void* __restrict__ eidx,
                                                      const int* __restrict__ flag64,
                                                      int* __restrict__ idx32) {
  const int i = blockIdx.x * 256 + threadIdx.x;
  if (i >= 2 * NEDGE) return;
  if (*flag64) idx32[i] = (int)((const long long*)eidx)[i];
  else         idx32[i] = ((const int*)eidx)[i];
}

// ---- setup 4: P = nodef@W1a + b1_eff, Q = nodef@W1c, packed bf16.
// TRANSPOSED row layout: dword d = l15*4 + k of node n holds features
// (32k+l15 | 32k+16+l15). One dwordx4 per (node, l15) covers k=0..3.
__global__ __launch_bounds__(512, 2) void pq_kernel(
    const float* __restrict__ nodef,
    const unsigned short* __restrict__ Bpack,
    const float* __restrict__ bias_eff,
    unsigned* __restrict__ Pp,
    unsigned* __restrict__ Qp) {
  __shared__ unsigned short lds_b[LDS_KS * NFRAG * 64 * 8];   // 65536 B

  const int tid  = threadIdx.x;
  const int lane = tid & 63;
  const int wid  = tid >> 6;
  const int l15  = lane & 15;
  const int kg   = lane >> 4;
  const int nb   = blockIdx.x * 256 + wid * 32;

#pragma unroll
  for (int i = 0; i < 8; ++i) {
    const char* g = (const char*)Bpack + (size_t)(i * 512 + tid) * 16;
    char*       l = (char*)lds_b + (size_t)(i * 512 + wid * 64) * 16;
    gload_lds16(g, l);
  }

  const int n0 = min(nb + l15, NNODE - 1);
  const int n1 = min(nb + 16 + l15, NNODE - 1);
  bf16x8 a0[4], a1[4];
#pragma unroll
  for (int ks = 0; ks < 4; ++ks) {
    const float* p0 = nodef + (size_t)n0 * HIDDEN + ks * 32 + kg * 8;
    const float* p1 = nodef + (size_t)n1 * HIDDEN + ks * 32 + kg * 8;
    a0[ks] = pack8(*(const f32x4*)p0, *(const f32x4*)(p0 + 4));
    a1[ks] = pack8(*(const f32x4*)p1, *(const f32x4*)(p1 + 4));
  }

  float bv[NFRAG];
#pragma unroll
  for (int f = 0; f < NFRAG; ++f) bv[f] = bias_eff[f * 16 + l15];

  __syncthreads();

  // P pass (W1a = ks 0..3), bias folded
  f32x4 acc[2][NFRAG];
#pragma unroll
  for (int m = 0; m < 2; ++m)
#pragma unroll
    for (int f = 0; f < NFRAG; ++f)
      acc[m][f] = (f32x4){bv[f], bv[f], bv[f], bv[f]};
#pragma unroll
  for (int ks = 0; ks < 4; ++ks)
#pragma unroll
    for (int f = 0; f < NFRAG; ++f) {
      bf16x8 bfr = *(const bf16x8*)(lds_b + ((ks * NFRAG + f) * 64 + lane) * 8);
      acc[0][f] = MFMA(a0[ks], bfr, acc[0][f]);
      acc[1][f] = MFMA(a1[ks], bfr, acc[1][f]);
    }
#pragma unroll
  for (int m = 0; m < 2; ++m)
#pragma unroll
    for (int r = 0; r < 4; ++r) {
      const int n = nb + m * 16 + kg * 4 + r;
      if (n < NNODE) {
        u32x4 sv;
#pragma unroll
        for (int k = 0; k < 4; ++k)
          sv[k] = cvt_pk_bf16(acc[m][2 * k][r], acc[m][2 * k + 1][r]);
        *(u32x4*)(Pp + (size_t)n * 64 + l15 * 4) = sv;
      }
    }

  // Q pass (W1c = ks 4..7)
#pragma unroll
  for (int m = 0; m < 2; ++m)
#pragma unroll
    for (int f = 0; f < NFRAG; ++f)
      acc[m][f] = (f32x4){0.f, 0.f, 0.f, 0.f};
#pragma unroll
  for (int ks = 0; ks < 4; ++ks)
#pragma unroll
    for (int f = 0; f < NFRAG; ++f) {
      bf16x8 bfr = *(const bf16x8*)(lds_b + (((ks + 4) * NFRAG + f) * 64 + lane) * 8);
      acc[0][f] = MFMA(a0[ks], bfr, acc[0][f]);
      acc[1][f] = MFMA(a1[ks], bfr, acc[1][f]);
    }
#pragma unroll
  for (int m = 0; m < 2; ++m)
#pragma unroll
    for (int r = 0; r < 4; ++r) {
      const int n = nb + m * 16 + kg * 4 + r;
      if (n < NNODE) {
        u32x4 sv;
#pragma unroll
        for (int k = 0; k < 4; ++k)
          sv[k] = cvt_pk_bf16(acc[m][2 * k][r], acc[m][2 * k + 1][r]);
        *(u32x4*)(Qp + (size_t)n * 64 + l15 * 4) = sv;
      }
    }
}

// ---- main: 256 thr = 4 waves x 32 edges, grid 6250, cap (256,3)=170 regs
// (proven no-spill for this body). Liveness-split: only ONE 8-gather set
// (P or Q) in flight at a time -> peak ~120 regs, so HW occupancy can rise
// beyond 3 blocks/CU on its own. sched_barrier keeps Q below P-consume.
__global__ __launch_bounds__(256, 3) void edge_attn_pq(
    const float* __restrict__ eattr,
    const void*  __restrict__ eidx,
    const int*   __restrict__ flag64,
    const unsigned* __restrict__ Pp,
    const unsigned* __restrict__ Qp,
    const unsigned short* __restrict__ Bpack,
    const float* __restrict__ W2,
    const float* __restrict__ b2,
    float* __restrict__ out) {
  const int tid   = threadIdx.x;
  const int lane  = tid & 63;
  const int wid   = tid >> 6;
  const int l15   = lane & 15;
  const int kg    = lane >> 4;
  const int ebase = blockIdx.x * 128 + wid * 32;

  const f32x4 zero4 = {0.f, 0.f, 0.f, 0.f};

  // indices (low dword of int64 / int32, uniform stride), C-layout rows:
  // edge = ebase + m*16 + kg*4 + r
  const int s = (*flag64) ? 2 : 1;
  const int* p32 = (const int*)eidx;
  int rn[2][4], cn[2][4];
#pragma unroll
  for (int m = 0; m < 2; ++m)
#pragma unroll
    for (int r = 0; r < 4; ++r) {
      const int e = ebase + m * 16 + kg * 4 + r;
      rn[m][r] = p32[(size_t)e * s];
      cn[m][r] = p32[((size_t)NEDGE + e) * s];
    }

  // issue P gathers only (8 dwordx4 in flight)
  u32x4 pu[2][4];
#pragma unroll
  for (int m = 0; m < 2; ++m)
#pragma unroll
    for (int r = 0; r < 4; ++r)
      pu[m][r] = *(const u32x4*)(Pp + (size_t)rn[m][r] * 64 + l15 * 4);

  // independent work under P latency: eattr, W2, b2, E-MFMA
  bf16x8 ae0, ae1;
  {
    const float* pe = eattr + (size_t)(ebase + l15) * EDGE_DIM + kg * 8;
    ae0 = pack8(*(const f32x4*)pe, *(const f32x4*)(pe + 4));
  }
  {
    const float* pe = eattr + (size_t)(ebase + 16 + l15) * EDGE_DIM + kg * 8;
    ae1 = pack8(*(const f32x4*)pe, *(const f32x4*)(pe + 4));
  }
  float w2v[NFRAG];
#pragma unroll
  for (int f = 0; f < NFRAG; ++f) w2v[f] = W2[f * 16 + l15];
  const float bias2 = b2[0];

  f32x4 acc[2][NFRAG];
#pragma unroll
  for (int f = 0; f < NFRAG; ++f) {
    bf16x8 bfr = *(const bf16x8*)(Bpack + ((8 * NFRAG + f) * 64 + lane) * 8);
    acc[0][f] = MFMA(ae0, bfr, zero4);
    acc[1][f] = MFMA(ae1, bfr, zero4);
  }

  // consume P (pu regs die here)
#pragma unroll
  for (int m = 0; m < 2; ++m)
#pragma unroll
    for (int r = 0; r < 4; ++r)
#pragma unroll
      for (int k = 0; k < 4; ++k) {
        const unsigned up = pu[m][r][k];
        acc[m][2 * k][r]     += __builtin_bit_cast(float, up << 16);
        acc[m][2 * k + 1][r] += __builtin_bit_cast(float, up & 0xffff0000u);
      }

  // fence: keep Q gathers below the P-consume so only one set is live
  __builtin_amdgcn_sched_barrier(0);

  // issue + consume Q
  u32x4 qu[2][4];
#pragma unroll
  for (int m = 0; m < 2; ++m)
#pragma unroll
    for (int r = 0; r < 4; ++r)
      qu[m][r] = *(const u32x4*)(Qp + (size_t)cn[m][r] * 64 + l15 * 4);
#pragma unroll
  for (int m = 0; m < 2; ++m)
#pragma unroll
    for (int r = 0; r < 4; ++r)
#pragma unroll
      for (int k = 0; k < 4; ++k) {
        const unsigned uq = qu[m][r][k];
        acc[m][2 * k][r]     += __builtin_bit_cast(float, uq << 16);
        acc[m][2 * k + 1][r] += __builtin_bit_cast(float, uq & 0xffff0000u);
      }

  // epilogue: relu + dot(W2), 16-lane xor-reduce, sigmoid
  float part[2][4];
#pragma unroll
  for (int m = 0; m < 2; ++m)
#pragma unroll
    for (int rr = 0; rr < 4; ++rr) {
      float s2 = 0.f;
#pragma unroll
      for (int f = 0; f < NFRAG; ++f) {
        float h = fmaxf(acc[m][f][rr], 0.f);
        s2 = fmaf(h, w2v[f], s2);
      }
      part[m][rr] = s2;
    }

#pragma unroll
  for (int mask = 1; mask < 16; mask <<= 1)
#pragma unroll
    for (int m = 0; m < 2; ++m)
#pragma unroll
      for (int rr = 0; rr < 4; ++rr)
        part[m][rr] += __shfl_xor(part[m][rr], mask, 64);

  if (l15 == 0) {
#pragma unroll
    for (int m = 0; m < 2; ++m)
#pragma unroll
      for (int rr = 0; rr < 4; ++rr) {
        float x = part[m][rr] + bias2;
        out[ebase + m * 16 + kg * 4 + rr] = 1.f / (1.f + __expf(-x));
      }
  }
}

// ---- R8 fallback main (bf16 nodes, LDS-staged B)
__global__ __launch_bounds__(512, 4) void edge_attn_kernel(
    const unsigned short* __restrict__ nbf,
    const float* __restrict__ eattr,
    const int*   __restrict__ idx32,
    const unsigned short* __restrict__ Bpack,
    const float* __restrict__ bias_eff,
    const float* __restrict__ W2,
    const float* __restrict__ b2,
    float* __restrict__ out) {
  __shared__ unsigned short lds_b[LDS_KS * NFRAG * 64 * 8];

  const int tid   = threadIdx.x;
  const int lane  = tid & 63;
  const int wid   = tid >> 6;
  const int l15   = lane & 15;
  const int kg    = lane >> 4;
  const int ebase = blockIdx.x * 256 + wid * 32;

#pragma unroll
  for (int i = 0; i < 8; ++i) {
    const char* g = (const char*)Bpack + (size_t)(i * 512 + tid) * 16;
    char*       l = (char*)lds_b + (size_t)(i * 512 + wid * 64) * 16;
    gload_lds16(g, l);
  }

  const int r0 = idx32[ebase + l15];
  const int r1 = idx32[ebase + 16 + l15];
  const int c0 = idx32[NEDGE + ebase + l15];
  const int c1 = idx32[NEDGE + ebase + 16 + l15];

  bf16x8 a0[4], a1[4];
#pragma unroll
  for (int ks = 0; ks < 4; ++ks) {
    a0[ks] = *(const bf16x8*)(nbf + (size_t)r0 * HIDDEN + kg * 8 + ks * 32);
    a1[ks] = *(const bf16x8*)(nbf + (size_t)r1 * HIDDEN + kg * 8 + ks * 32);
  }

  __syncthreads();

  f32x4 acc[2][NFRAG];
#pragma unroll
  for (int m = 0; m < 2; ++m)
#pragma unroll
    for (int f = 0; f < NFRAG; ++f)
      acc[m][f] = (f32x4){0.f, 0.f, 0.f, 0.f};

#pragma unroll
  for (int ks = 0; ks < 4; ++ks)
#pragma unroll
    for (int f = 0; f < NFRAG; ++f) {
      bf16x8 bfr = *(const bf16x8*)(lds_b + ((ks * NFRAG + f) * 64 + lane) * 8);
      acc[0][f] = MFMA(a0[ks], bfr, acc[0][f]);
      acc[1][f] = MFMA(a1[ks], bfr, acc[1][f]);
    }

  __builtin_amdgcn_sched_barrier(0);

#pragma unroll
  for (int ks = 0; ks < 4; ++ks) {
    a0[ks] = *(const bf16x8*)(nbf + (size_t)c0 * HIDDEN + kg * 8 + ks * 32);
    a1[ks] = *(const bf16x8*)(nbf + (size_t)c1 * HIDDEN + kg * 8 + ks * 32);
  }

#pragma unroll
  for (int ks = 0; ks < 4; ++ks)
#pragma unroll
    for (int f = 0; f < NFRAG; ++f) {
      bf16x8 bfr = *(const bf16x8*)(lds_b + (((ks + 4) * NFRAG + f) * 64 + lane) * 8);
      acc[0][f] = MFMA(a0[ks], bfr, acc[0][f]);
      acc[1][f] = MFMA(a1[ks], bfr, acc[1][f]);
    }

  __builtin_amdgcn_sched_barrier(0);

  bf16x8 ae0, ae1;
  {
    const float* pe = eattr + (size_t)(ebase + l15) * EDGE_DIM + kg * 8;
    ae0 = pack8(*(const f32x4*)pe, *(const f32x4*)(pe + 4));
  }
  {
    const float* pe = eattr + (size_t)(ebase + 16 + l15) * EDGE_DIM + kg * 8;
    ae1 = pack8(*(const f32x4*)pe, *(const f32x4*)(pe + 4));
  }
#pragma unroll
  for (int f = 0; f < NFRAG; ++f) {
    bf16x8 bfr = *(const bf16x8*)(Bpack + ((8 * NFRAG + f) * 64 + lane) * 8);
    acc[0][f] = MFMA(ae0, bfr, acc[0][f]);
    acc[1][f] = MFMA(ae1, bfr, acc[1][f]);
  }

  float w2v[NFRAG], bv[NFRAG];
#pragma unroll
  for (int f = 0; f < NFRAG; ++f) {
    w2v[f] = W2[f * 16 + l15];
    bv[f]  = bias_eff[f * 16 + l15];
  }
  const float bias2 = b2[0];

  float part[2][4];
#pragma unroll
  for (int m = 0; m < 2; ++m)
#pragma unroll
    for (int rr = 0; rr < 4; ++rr) {
      float s = 0.f;
#pragma unroll
      for (int f = 0; f < NFRAG; ++f) {
        float h = fmaxf(acc[m][f][rr] + bv[f], 0.f);
        s = fmaf(h, w2v[f], s);
      }
      part[m][rr] = s;
    }

#pragma unroll
  for (int mask = 1; mask < 16; mask <<= 1)
#pragma unroll
    for (int m = 0; m < 2; ++m)
#pragma unroll
      for (int rr = 0; rr < 4; ++rr)
        part[m][rr] += __shfl_xor(part[m][rr], mask, 64);

  if (l15 == 0) {
#pragma unroll
    for (int m = 0; m < 2; ++m)
#pragma unroll
      for (int rr = 0; rr < 4; ++rr) {
        float x = part[m][rr] + bias2;
        out[ebase + m * 16 + kg * 4 + rr] = 1.f / (1.f + __expf(-x));
      }
  }
}

// ---- last-resort fallback (fp32 gathers, global B)
__global__ __launch_bounds__(256) void edge_attn_kernel_fp32(
    const float* __restrict__ nodef,
    const float* __restrict__ eattr,
    const void*  __restrict__ eidx,
    const unsigned short* __restrict__ Bpack,
    const float* __restrict__ bias_eff,
    const float* __restrict__ W2,
    const float* __restrict__ b2,
    const int*   __restrict__ flag64,
    float* __restrict__ out) {
  const int lane  = threadIdx.x & 63;
  const int wid   = threadIdx.x >> 6;
  const int ebase = blockIdx.x * 128 + wid * 32;
  const int l15   = lane & 15;
  const int kg    = lane >> 4;
  const int koff  = kg * 8;
  const int e0 = ebase + l15;
  const int e1 = e0 + 16;

  long r0, c0, r1, c1;
  if (*flag64) {
    const long long* p = (const long long*)eidx;
    r0 = (long)p[e0];          r1 = (long)p[e1];
    c0 = (long)p[NEDGE + e0];  c1 = (long)p[NEDGE + e1];
  } else {
    const int* p = (const int*)eidx;
    r0 = p[e0];          r1 = p[e1];
    c0 = p[NEDGE + e0];  c1 = p[NEDGE + e1];
  }

  f32x4 acc[2][NFRAG];
#pragma unroll
  for (int m = 0; m < 2; ++m)
#pragma unroll
    for (int f = 0; f < NFRAG; ++f)
      acc[m][f] = (f32x4){0.f, 0.f, 0.f, 0.f};

#pragma unroll 1
  for (int ks = 0; ks < KSTEPS; ++ks) {
    const float *p0, *p1;
    if (ks < 4)      { p0 = nodef + r0 * HIDDEN + ks * 32;       p1 = nodef + r1 * HIDDEN + ks * 32; }
    else if (ks < 8) { p0 = nodef + c0 * HIDDEN + (ks - 4) * 32; p1 = nodef + c1 * HIDDEN + (ks - 4) * 32; }
    else             { p0 = eattr + (long)e0 * EDGE_DIM;         p1 = eattr + (long)e1 * EDGE_DIM; }

    f32x4 lo0 = *(const f32x4*)(p0 + koff);
    f32x4 hi0 = *(const f32x4*)(p0 + koff + 4);
    f32x4 lo1 = *(const f32x4*)(p1 + koff);
    f32x4 hi1 = *(const f32x4*)(p1 + koff + 4);
    bf16x8 a0 = pack8(lo0, hi0);
    bf16x8 a1 = pack8(lo1, hi1);

#pragma unroll
    for (int f = 0; f < NFRAG; ++f) {
      bf16x8 bfr = *(const bf16x8*)(Bpack + ((ks * NFRAG + f) * 64 + lane) * 8);
      acc[0][f] = MFMA(a0, bfr, acc[0][f]);
      acc[1][f] = MFMA(a1, bfr, acc[1][f]);
    }
  }

  float w2v[NFRAG], bv[NFRAG];
#pragma unroll
  for (int f = 0; f < NFRAG; ++f) {
    w2v[f] = W2[f * 16 + l15];
    bv[f]  = bias_eff[f * 16 + l15];
  }
  const float bias2 = b2[0];

  float part[2][4];
#pragma unroll
  for (int m = 0; m < 2; ++m)
#pragma unroll
    for (int r = 0; r < 4; ++r) {
      float s = 0.f;
#pragma unroll
      for (int f = 0; f < NFRAG; ++f) {
        float h = acc[m][f][r] + bv[f];
        h = fmaxf(h, 0.f);
        s = fmaf(h, w2v[f], s);
      }
      part[m][r] = s;
    }

#pragma unroll
  for (int mask = 1; mask < 16; mask <<= 1)
#pragma unroll
    for (int m = 0; m < 2; ++m)
#pragma unroll
      for (int r = 0; r < 4; ++r)
        part[m][r] += __shfl_xor(part[m][r], mask, 64);

  if (l15 == 0) {
#pragma unroll
    for (int m = 0; m < 2; ++m)
#pragma unroll
      for (int r = 0; r < 4; ++r) {
        float x = part[m][r] + bias2;
        out[ebase + m * 16 + kg * 4 + r] = 1.f / (1.f + __expf(-x));
      }
  }
}

extern "C" void kernel_launch(void* const* d_in, const int* in_sizes, int n_in,
                              void* d_out, int out_size, void* d_ws, size_t ws_size,
                              hipStream_t stream) {
  const float* nodef  = (const float*)d_in[0];
  const float* eattr  = (const float*)d_in[1];
  const float* W_edge = (const float*)d_in[2];
  const float* b_edge = (const float*)d_in[3];
  const float* W1     = (const float*)d_in[4];
  const float* b1     = (const float*)d_in[5];
  const float* W2     = (const float*)d_in[6];
  const float* b2     = (const float*)d_in[7];
  const void*  eidx   = d_in[8];

  unsigned short* Bpack    = (unsigned short*)d_ws;
  float*          bias_eff = (float*)((char*)d_ws + BIAS_OFF_BYTES);
  int*            flag64   = (int*)((char*)d_ws + FLAG_OFF_BYTES);

  setup_kernel<<<dim3(37), dim3(128), 0, stream>>>(W_edge, b_edge, W1, b1, eidx,
                                                   Bpack, bias_eff, flag64);

  if (ws_size >= (size_t)WS_NEW) {
    unsigned* Pp = (unsigned*)((char*)d_ws + PP_OFF);
    unsigned* Qp = (unsigned*)((char*)d_ws + QP_OFF);
    pq_kernel<<<dim3((NNODE + 255) / 256), dim3(512), 0, stream>>>(nodef, Bpack, bias_eff, Pp, Qp);
    edge_attn_pq<<<dim3(NEDGE / 128), dim3(256), 0, stream>>>(
        eattr, eidx, flag64, Pp, Qp, Bpack, W2, b2, (float*)d_out);
  } else if (ws_size >= (size_t)WS_R8) {
    unsigned short* nbf   = (unsigned short*)((char*)d_ws + NODE_OFF_BYTES);
    int*            idx32 = (int*)((char*)d_ws + IDX_OFF_BYTES);
    cvt_idx_kernel<<<dim3((2 * NEDGE + 255) / 256), dim3(256), 0, stream>>>(eidx, flag64, idx32);
    cvt_nodes_kernel<<<dim3((NNODE * HIDDEN / 8 + 255) / 256), dim3(256), 0, stream>>>(nodef, nbf);
    edge_attn_kernel<<<dim3(NEDGE / 256), dim3(512), 0, stream>>>(
        nbf, eattr, idx32, Bpack, bias_eff, W2, b2, (float*)d_out);
  } else {
    edge_attn_kernel_fp32<<<dim3(NEDGE / 128), dim3(256), 0, stream>>>(
        nodef, eattr, eidx, Bpack, bias_eff, W2, b2, flag64, (float*)d_out);
  }
}